// Round 12
// baseline (162.283 us; speedup 1.0000x reference)
//
#include <hip/hip_runtime.h>
#include <math.h>

#define B_    16
#define N_    8192
#define D_    256
#define BN_   32
#define R_    4
#define LOGN  13

typedef float  f32x4  __attribute__((ext_vector_type(4)));
typedef short  s16x8  __attribute__((ext_vector_type(8)));

// LDS XOR-swizzle: breaks power-of-2 stride bank aliasing for 8B elements.
// Bijective (low 4 bits XOR'd with higher bits); adjacent pairs stay adjacent.
__device__ __forceinline__ int SW(int i) {
    return i ^ ((i >> 4) & 15) ^ ((i >> 8) & 15);
}

// ---------------------------------------------------------------------------
// Morton helpers (exact replica of reference bit-interleave)
// ---------------------------------------------------------------------------
__device__ __forceinline__ unsigned long long interleave3(unsigned long long v) {
    v = v & 2097151ULL;
    v = v | (v << 32);
    v = v & 8725724278095871ULL;
    v = v | ((v << 16) & 8725728556220671ULL);
    v = v | ((v << 8)  & 282506020581391ULL);
    v = v | ((v << 4)  & 294878547030211ULL);
    v = v | ((v << 2)  & 321685687669321ULL);
    return v;
}

__device__ __forceinline__ long long quant10(float c) {
    long long v = (long long)(c * 1023.0f);
    v = v < 0 ? 0 : (v > 1023 ? 1023 : v);
    return v;
}

__device__ __forceinline__ unsigned short f2bf(float f) {
    unsigned u = __float_as_uint(f);
    u = (u + 0x7FFF + ((u >> 16) & 1)) >> 16;   // RNE
    return (unsigned short)u;
}

__device__ __forceinline__ unsigned cvtpk_bf16(float lo, float hi) {
    unsigned r;
    asm("v_cvt_pk_bf16_f32 %0, %1, %2" : "=v"(r) : "v"(lo), "v"(hi));
    return r;
}

// ---------------------------------------------------------------------------
// P0: prep — G = Wu @ V  [256,4]  and  Wd packed to bf16 [32][256] row-major.
// ---------------------------------------------------------------------------
__global__ void prep_kernel(const float* __restrict__ Wu, const float* __restrict__ V,
                            const float* __restrict__ Wd,
                            float* __restrict__ G, unsigned short* __restrict__ wdpack) {
    const int t = threadIdx.x;   // 256
    for (int r = 0; r < R_; ++r) {
        float s = 0.0f;
        for (int kk = 0; kk < BN_; ++kk) s += Wu[t * BN_ + kk] * V[kk * R_ + r];
        G[t * R_ + r] = s;
    }
    for (int i = t; i < BN_ * 256; i += 256) {
        const int row = i >> 8, col = i & 255;
        wdpack[i] = f2bf(Wd[row * 257 + col]);
    }
}

// ---------------------------------------------------------------------------
// FAT kernel: blocks 0..31 = sort1 (local 4096-key bitonic, LDS-swizzled);
// blocks 32.. = natural-order MFMA zraw = Wd·x with direct global->reg
// B-fragments (no LDS in the streaming branch).
// ---------------------------------------------------------------------------
__global__ __launch_bounds__(512)
void fat_kernel(const float* __restrict__ x,
                const float* __restrict__ coords,
                const unsigned short* __restrict__ wdpack,
                unsigned long long* __restrict__ keys,
                float* __restrict__ z_pk) {
    extern __shared__ char fsm[];
    const int bid = blockIdx.x;
    const int t   = threadIdx.x;

    if (bid < 2 * B_) {
        // ================= sort1: local bitonic, sizes 2..4096 =================
        unsigned long long* skey = (unsigned long long*)fsm;   // 32 KB
        const int b = bid >> 1;
        const int h = bid & 1;
        const int gbase = h * 4096;

        for (int i = t; i < 4096; i += 512) {
            const int gi = gbase + i;
            const float* c = coords + ((size_t)b * N_ + gi) * 3;
            unsigned long long mx = interleave3((unsigned long long)quant10(c[0]));
            unsigned long long my = interleave3((unsigned long long)quant10(c[1]));
            unsigned long long mz = interleave3((unsigned long long)quant10(c[2]));
            unsigned long long m = mx | (my << 1) | (mz << 2);
            skey[SW(i)] = (m << LOGN) | (unsigned long long)gi;
        }
        __syncthreads();

        for (int size = 2; size <= 4096; size <<= 1) {
            for (int s = size >> 1; s > 0; s >>= 1) {
                int i_[4];
                unsigned long long a_[4], b_[4];
                #pragma unroll
                for (int u = 0; u < 4; ++u) {
                    int p  = t + u * 512;            // 2048 pairs
                    int jj = p & (s - 1);
                    int i  = ((p - jj) << 1) + jj;
                    i_[u] = i; a_[u] = skey[SW(i)]; b_[u] = skey[SW(i + s)];
                }
                #pragma unroll
                for (int u = 0; u < 4; ++u) {
                    bool up = (((gbase + i_[u]) & size) == 0);
                    unsigned long long lo = a_[u] < b_[u] ? a_[u] : b_[u];
                    unsigned long long hi = a_[u] < b_[u] ? b_[u] : a_[u];
                    skey[SW(i_[u])]     = up ? lo : hi;
                    skey[SW(i_[u] + s)] = up ? hi : lo;
                }
                __syncthreads();
            }
        }
        for (int i = t; i < 4096; i += 512)
            keys[(size_t)b * N_ + gbase + i] = skey[SW(i)];
    } else {
        // ===== zgemm_nat: 128 rows/block, direct global->reg fragments =====
        const int zb  = bid - 2 * B_;           // 0..1023
        const int b   = zb >> 6;
        const int m0  = (zb & 63) << 7;         // 128-row tile base
        const int w   = t >> 6;                 // 0..7
        const int l   = t & 63;
        const int lg  = l >> 4;
        const int lm  = l & 15;

        s16x8 wf0[8], wf1[8];
        #pragma unroll
        for (int kc = 0; kc < 8; ++kc) {
            wf0[kc] = *(const s16x8*)(wdpack + lm * 256        + kc * 32 + lg * 8);
            wf1[kc] = *(const s16x8*)(wdpack + (lm + 16) * 256 + kc * 32 + lg * 8);
        }

        const int xr = w * 16 + lm;             // row within tile
        const float* xrow = x + ((size_t)(b * N_ + m0 + xr)) * D_;

        f32x4 acc0 = {0.f, 0.f, 0.f, 0.f};
        f32x4 acc1 = {0.f, 0.f, 0.f, 0.f};
        #pragma unroll
        for (int kc = 0; kc < 8; ++kc) {
            const float4 va = *(const float4*)(xrow + kc * 32 + lg * 8);
            const float4 vb = *(const float4*)(xrow + kc * 32 + lg * 8 + 4);
            union { s16x8 v; unsigned u[4]; } bu_;
            bu_.u[0] = cvtpk_bf16(va.x, va.y);
            bu_.u[1] = cvtpk_bf16(va.z, va.w);
            bu_.u[2] = cvtpk_bf16(vb.x, vb.y);
            bu_.u[3] = cvtpk_bf16(vb.z, vb.w);
            acc0 = __builtin_amdgcn_mfma_f32_16x16x32_bf16(wf0[kc], bu_.v, acc0, 0, 0, 0);
            acc1 = __builtin_amdgcn_mfma_f32_16x16x32_bf16(wf1[kc], bu_.v, acc1, 0, 0, 0);
        }

        // natural-order, fully coalesced 128B-per-point store (raw)
        const int m = m0 + xr;
        float* zb_ = z_pk + ((size_t)(b * N_ + m)) * BN_;
        float4 v0, v1;
        v0.x = acc0[0]; v0.y = acc0[1]; v0.z = acc0[2]; v0.w = acc0[3];
        v1.x = acc1[0]; v1.y = acc1[1]; v1.z = acc1[2]; v1.w = acc1[3];
        *(float4*)(zb_ + lg * 4)      = v0;
        *(float4*)(zb_ + 16 + lg * 4) = v1;
    }
}

// ---------------------------------------------------------------------------
// S2: 32 blocks (b, half). Load stage performs the stride-4096 global
// compare (min for half0 / max for half1), then strides 2048..1 in LDS
// (swizzled). Emits order[b][p].
// ---------------------------------------------------------------------------
__global__ __launch_bounds__(1024)
void sort2_kernel(const unsigned long long* __restrict__ keys, int* __restrict__ order) {
    __shared__ unsigned long long skey[4096];    // 32 KB
    const int b = blockIdx.x >> 1;
    const int h = blockIdx.x & 1;
    const int t = threadIdx.x;
    const int gbase = h * 4096;

    for (int i = t; i < 4096; i += 1024) {
        unsigned long long a = keys[(size_t)b * N_ + i];
        unsigned long long c = keys[(size_t)b * N_ + 4096 + i];
        unsigned long long lo = a < c ? a : c;
        unsigned long long hi = a < c ? c : a;
        skey[SW(i)] = h == 0 ? lo : hi;
    }
    __syncthreads();

    for (int s = 2048; s > 0; s >>= 1) {
        int i_[2];
        unsigned long long a_[2], b_[2];
        #pragma unroll
        for (int u = 0; u < 2; ++u) {
            int p  = t + u * 1024;
            int jj = p & (s - 1);
            int i  = ((p - jj) << 1) + jj;
            i_[u] = i; a_[u] = skey[SW(i)]; b_[u] = skey[SW(i + s)];
        }
        #pragma unroll
        for (int u = 0; u < 2; ++u) {
            unsigned long long lo = a_[u] < b_[u] ? a_[u] : b_[u];
            unsigned long long hi = a_[u] < b_[u] ? b_[u] : a_[u];
            skey[SW(i_[u])]     = lo;
            skey[SW(i_[u] + s)] = hi;
        }
        __syncthreads();
    }
    for (int i = t; i < 4096; i += 1024)
        order[b * N_ + gbase + i] = (int)(skey[SW(i)] & (unsigned long long)(N_ - 1));
}

// ---------------------------------------------------------------------------
// ZG: permutation + radius + bias + relu + transpose to k-major.
// ---------------------------------------------------------------------------
__global__ __launch_bounds__(512)
void zgather_kernel(const float* __restrict__ z_pk,
                    const float* __restrict__ coords,
                    const float* __restrict__ Wd,
                    const float* __restrict__ bd,
                    const int*   __restrict__ order,
                    float*       __restrict__ z_kp) {
    __shared__ float ltile[64][33];
    __shared__ float sWdLast[BN_];
    __shared__ float sbd[BN_];
    const int blk = blockIdx.x;           // 2048
    const int b   = blk >> 7;
    const int p0  = (blk & 127) << 6;
    const int t   = threadIdx.x;

    if (t < BN_) { sWdLast[t] = Wd[(size_t)t * 257 + 256]; sbd[t] = bd[t]; }
    __syncthreads();

    {
        const int sl = t >> 3;            // 0..63 sorted slots
        const int kc = t & 7;             // 8 float4 chunks of 32 channels
        const int p  = p0 + sl;
        const int od = order[b * N_ + p];
        float4 v = *(const float4*)(z_pk + ((size_t)(b * N_ + od)) * BN_ + kc * 4);
        const float* c = coords + ((size_t)(b * N_ + p)) * 3;
        const float rr = sqrtf(c[0] * c[0] + c[1] * c[1] + c[2] * c[2]);
        v.x = fmaxf(v.x + rr * sWdLast[kc * 4 + 0] + sbd[kc * 4 + 0], 0.0f);
        v.y = fmaxf(v.y + rr * sWdLast[kc * 4 + 1] + sbd[kc * 4 + 1], 0.0f);
        v.z = fmaxf(v.z + rr * sWdLast[kc * 4 + 2] + sbd[kc * 4 + 2], 0.0f);
        v.w = fmaxf(v.w + rr * sWdLast[kc * 4 + 3] + sbd[kc * 4 + 3], 0.0f);
        ltile[sl][kc * 4 + 0] = v.x;
        ltile[sl][kc * 4 + 1] = v.y;
        ltile[sl][kc * 4 + 2] = v.z;
        ltile[sl][kc * 4 + 3] = v.w;
    }
    __syncthreads();

    {
        const int k  = t >> 4;            // 0..31
        const int pc = t & 15;            // 16 x float4 along p
        float4 o;
        o.x = ltile[pc * 4 + 0][k];
        o.y = ltile[pc * 4 + 1][k];
        o.z = ltile[pc * 4 + 2][k];
        o.w = ltile[pc * 4 + 3][k];
        *(float4*)(z_kp + (size_t)(b * BN_ + k) * N_ + p0 + pc * 4) = o;
    }
}

// ---------------------------------------------------------------------------
// K4: PAIR-PACKED spectral filter, LDS accesses XOR-swizzled (SW).
// ---------------------------------------------------------------------------
__device__ __forceinline__ float2 cmul(float2 a, float2 b) {
    return make_float2(a.x * b.x - a.y * b.y, a.x * b.y + a.y * b.x);
}
__device__ __forceinline__ float2 sdmix(float S, float D, float2 P, float2 Q) {
    return make_float2(S * P.x + D * Q.x, S * P.y - D * Q.y);
}

__global__ __launch_bounds__(512)
void fft_filter_kernel(float* __restrict__ zy,
                       const float* __restrict__ logit_d) {
    extern __shared__ float2 cbuf[];   // 64 KB

    const int bk = blockIdx.x;     // 256 = B_ * 16
    const int b  = bk >> 4;
    const int kp = bk & 15;
    const int t  = threadIdx.x;

    float* row1 = zy + (size_t)(b * BN_ + 2 * kp) * N_;
    float* row2 = row1 + N_;

    float d1 = fminf(fmaxf(logit_d[2 * kp],     -10.0f), 10.0f);
    float d2 = fminf(fmaxf(logit_d[2 * kp + 1], -10.0f), 10.0f);

    const float cpi  = 3.14159265358979323846f;
    const float c2pi = 6.28318530717958647692f;
    const float A    = c2pi * 8192.0f / 8191.0f;

    const float Eh1 = __expf(-0.5f * A * d1), E1 = Eh1 * Eh1;
    const float Eh2 = __expf(-0.5f * A * d2), E2 = Eh2 * Eh2;

    // ---- F1: fused forward (4096,2048), complex input from GLOBAL ----
    {
        const int h = 4096, hh = 2048;
        #pragma unroll
        for (int u = 0; u < 4; ++u) {
            const int i0 = t + u * 512;
            float2 c0 = make_float2(row1[i0],            row2[i0]);
            float2 c1 = make_float2(row1[i0 + hh],       row2[i0 + hh]);
            float2 c2 = make_float2(row1[i0 + h],        row2[i0 + h]);
            float2 c3 = make_float2(row1[i0 + h + hh],   row2[i0 + h + hh]);
            float sA, cA;
            __sincosf(-cpi * (float)i0 / (float)h, &sA, &cA);
            const float2 twA1 = make_float2(cA, sA);
            const float2 twA2 = make_float2(sA, -cA);
            const float2 twB  = make_float2(2.0f * cA * cA - 1.0f, 2.0f * sA * cA);
            float2 a0 = make_float2(c0.x + c2.x, c0.y + c2.y);
            float2 a1 = make_float2(c1.x + c3.x, c1.y + c3.y);
            float2 b0 = cmul(make_float2(c0.x - c2.x, c0.y - c2.y), twA1);
            float2 b1 = cmul(make_float2(c1.x - c3.x, c1.y - c3.y), twA2);
            cbuf[SW(i0)]          = make_float2(a0.x + a1.x, a0.y + a1.y);
            cbuf[SW(i0 + hh)]     = cmul(make_float2(a0.x - a1.x, a0.y - a1.y), twB);
            cbuf[SW(i0 + h)]      = make_float2(b0.x + b1.x, b0.y + b1.y);
            cbuf[SW(i0 + h + hh)] = cmul(make_float2(b0.x - b1.x, b0.y - b1.y), twB);
        }
        __syncthreads();
    }

    // ---- F2..F6: fused forward (h, h/2) for h = 1024,256,64,16,4 ----
    #pragma unroll
    for (int h = 1024; h >= 4; h >>= 2) {
        const int hh = h >> 1;
        #pragma unroll
        for (int u = 0; u < 4; ++u) {
            const int q   = t + u * 512;
            const int jj  = q & (hh - 1);
            const int i0  = ((q - jj) << 2) + jj;
            float2 c0 = cbuf[SW(i0)];
            float2 c1 = cbuf[SW(i0 + hh)];
            float2 c2 = cbuf[SW(i0 + h)];
            float2 c3 = cbuf[SW(i0 + h + hh)];
            float sA, cA;
            __sincosf(-cpi * (float)jj / (float)h, &sA, &cA);
            const float2 twA1 = make_float2(cA, sA);
            const float2 twA2 = make_float2(sA, -cA);
            const float2 twB  = make_float2(2.0f * cA * cA - 1.0f, 2.0f * sA * cA);
            float2 a0 = make_float2(c0.x + c2.x, c0.y + c2.y);
            float2 a1 = make_float2(c1.x + c3.x, c1.y + c3.y);
            float2 b0 = cmul(make_float2(c0.x - c2.x, c0.y - c2.y), twA1);
            float2 b1 = cmul(make_float2(c1.x - c3.x, c1.y - c3.y), twA2);
            cbuf[SW(i0)]          = make_float2(a0.x + a1.x, a0.y + a1.y);
            cbuf[SW(i0 + hh)]     = cmul(make_float2(a0.x - a1.x, a0.y - a1.y), twB);
            cbuf[SW(i0 + h)]      = make_float2(b0.x + b1.x, b0.y + b1.y);
            cbuf[SW(i0 + h + hh)] = cmul(make_float2(b0.x - b1.x, b0.y - b1.y), twB);
        }
        __syncthreads();
    }

    // ---- M: fwd h=1 + Hermitian unpack * Hsym + repack + inv h=1 ----
    {
        #pragma unroll
        for (int v = 0; v < 4; ++v) {
            const int u = t + v * 512;
            if (u == 0) {
                {   // SW(i)=i for i<16
                    float2 g0 = cbuf[0], g1 = cbuf[1];
                    float2 Pa = make_float2(g0.x + g1.x, g0.y + g1.y);
                    float2 Pb = make_float2(g0.x - g1.x, g0.y - g1.y);
                    float2 Ra = Pa;
                    float Sb = 0.5f * (Eh1 + Eh2), Db = 0.5f * (Eh1 - Eh2);
                    float2 Rb = sdmix(Sb, Db, Pb, Pb);
                    cbuf[0] = make_float2(Ra.x + Rb.x, Ra.y + Rb.y);
                    cbuf[1] = make_float2(Ra.x - Rb.x, Ra.y - Rb.y);
                }
                {
                    float wu = c2pi * 2048.0f / 8191.0f;
                    float h1 = __expf(-wu * d1), h2 = __expf(-wu * d2);
                    float h1b = h1 * Eh1, h2b = h2 * Eh2;
                    float Hs1a = 0.5f * (h1 + E1 / h1);
                    float Hs2a = 0.5f * (h2 + E2 / h2);
                    float Hs1b = 0.5f * (h1b + E1 / h1b);
                    float Hs2b = 0.5f * (h2b + E2 / h2b);
                    float Sa = 0.5f * (Hs1a + Hs2a), Da = 0.5f * (Hs1a - Hs2a);
                    float Sb = 0.5f * (Hs1b + Hs2b), Db = 0.5f * (Hs1b - Hs2b);
                    float2 g0 = cbuf[2], g1 = cbuf[3];
                    float2 Pa = make_float2(g0.x + g1.x, g0.y + g1.y);
                    float2 Pb = make_float2(g0.x - g1.x, g0.y - g1.y);
                    float2 Ra = sdmix(Sa, Da, Pa, Pb);
                    float2 Rb = sdmix(Sb, Db, Pb, Pa);
                    cbuf[2] = make_float2(Ra.x + Rb.x, Ra.y + Rb.y);
                    cbuf[3] = make_float2(Ra.x - Rb.x, Ra.y - Rb.y);
                }
            } else {
                const int u2 = 4096 - u;
                const int c  = (int)(__brev((unsigned)u)  >> 20);
                const int c2 = (int)(__brev((unsigned)u2) >> 20);
                const int s0 = SW(2 * c),  s1 = SW(2 * c + 1);
                const int s2 = SW(2 * c2), s3 = SW(2 * c2 + 1);
                float2 g0 = cbuf[s0], g1 = cbuf[s1];
                float2 q0 = cbuf[s2], q1 = cbuf[s3];
                float2 Pa  = make_float2(g0.x + g1.x, g0.y + g1.y);
                float2 Pb  = make_float2(g0.x - g1.x, g0.y - g1.y);
                float2 Pa2 = make_float2(q0.x + q1.x, q0.y + q1.y);
                float2 Pb2 = make_float2(q0.x - q1.x, q0.y - q1.y);
                float wu = c2pi * (float)u / 8191.0f;
                float h1 = __expf(-wu * d1), h2 = __expf(-wu * d2);
                float h1b = h1 * Eh1, h2b = h2 * Eh2;
                float Hs1a = 0.5f * (h1 + E1 / h1);
                float Hs2a = 0.5f * (h2 + E2 / h2);
                float Hs1b = 0.5f * (h1b + E1 / h1b);
                float Hs2b = 0.5f * (h2b + E2 / h2b);
                float Sa = 0.5f * (Hs1a + Hs2a), Da = 0.5f * (Hs1a - Hs2a);
                float Sb = 0.5f * (Hs1b + Hs2b), Db = 0.5f * (Hs1b - Hs2b);
                float2 Ra  = sdmix(Sa, Da, Pa,  Pb2);
                float2 Rb2 = sdmix(Sa, Da, Pb2, Pa);
                float2 Rb  = sdmix(Sb, Db, Pb,  Pa2);
                float2 Ra2 = sdmix(Sb, Db, Pa2, Pb);
                cbuf[s0] = make_float2(Ra.x + Rb.x,   Ra.y + Rb.y);
                cbuf[s1] = make_float2(Ra.x - Rb.x,   Ra.y - Rb.y);
                cbuf[s2] = make_float2(Ra2.x + Rb2.x, Ra2.y + Rb2.y);
                cbuf[s3] = make_float2(Ra2.x - Rb2.x, Ra2.y - Rb2.y);
            }
        }
        __syncthreads();
    }

    // ---- I1..I5: fused inverse (h, 2h) for h = 2,8,32,128,512 ----
    #pragma unroll
    for (int h = 2; h <= 512; h <<= 2) {
        #pragma unroll
        for (int u = 0; u < 4; ++u) {
            const int q  = t + u * 512;
            const int jj = q & (h - 1);
            const int i0 = ((q - jj) << 2) + jj;
            float2 c0 = cbuf[SW(i0)];
            float2 c1 = cbuf[SW(i0 + h)];
            float2 c2 = cbuf[SW(i0 + 2 * h)];
            float2 c3 = cbuf[SW(i0 + 3 * h)];
            float sa, ca;
            __sincosf(cpi * (float)jj / (float)(2 * h), &sa, &ca);
            const float2 tw1  = make_float2(2.0f * ca * ca - 1.0f, 2.0f * sa * ca);
            const float2 tw2a = make_float2(ca, sa);
            const float2 tw2b = make_float2(-sa, ca);
            float2 t0 = cmul(c1, tw1);
            float2 a0 = make_float2(c0.x + t0.x, c0.y + t0.y);
            float2 a1 = make_float2(c0.x - t0.x, c0.y - t0.y);
            float2 t1 = cmul(c3, tw1);
            float2 b0 = make_float2(c2.x + t1.x, c2.y + t1.y);
            float2 b1 = make_float2(c2.x - t1.x, c2.y - t1.y);
            float2 t2 = cmul(b0, tw2a);
            cbuf[SW(i0)]         = make_float2(a0.x + t2.x, a0.y + t2.y);
            cbuf[SW(i0 + 2 * h)] = make_float2(a0.x - t2.x, a0.y - t2.y);
            float2 t3 = cmul(b1, tw2b);
            cbuf[SW(i0 + h)]     = make_float2(a1.x + t3.x, a1.y + t3.y);
            cbuf[SW(i0 + 3 * h)] = make_float2(a1.x - t3.x, a1.y - t3.y);
        }
        __syncthreads();
    }

    // ---- I6: fused inverse (2048, 4096), scaled split write to GLOBAL ----
    {
        const int h = 2048;
        const float inv = 1.0f / (float)N_;
        #pragma unroll
        for (int u = 0; u < 4; ++u) {
            const int jj = t + u * 512;
            const int i0 = jj;
            float2 c0 = cbuf[SW(i0)];
            float2 c1 = cbuf[SW(i0 + h)];
            float2 c2 = cbuf[SW(i0 + 2 * h)];
            float2 c3 = cbuf[SW(i0 + 3 * h)];
            float sa, ca;
            __sincosf(cpi * (float)jj / (float)(2 * h), &sa, &ca);
            const float2 tw1  = make_float2(2.0f * ca * ca - 1.0f, 2.0f * sa * ca);
            const float2 tw2a = make_float2(ca, sa);
            const float2 tw2b = make_float2(-sa, ca);
            float2 t0 = cmul(c1, tw1);
            float2 a0 = make_float2(c0.x + t0.x, c0.y + t0.y);
            float2 a1 = make_float2(c0.x - t0.x, c0.y - t0.y);
            float2 t1 = cmul(c3, tw1);
            float2 b0 = make_float2(c2.x + t1.x, c2.y + t1.y);
            float2 b1 = make_float2(c2.x - t1.x, c2.y - t1.y);
            float2 t2 = cmul(b0, tw2a);
            float2 o0 = make_float2(a0.x + t2.x, a0.y + t2.y);
            float2 o2 = make_float2(a0.x - t2.x, a0.y - t2.y);
            float2 t3 = cmul(b1, tw2b);
            float2 o1 = make_float2(a1.x + t3.x, a1.y + t3.y);
            float2 o3 = make_float2(a1.x - t3.x, a1.y - t3.y);
            row1[i0]         = o0.x * inv;  row2[i0]         = o0.y * inv;
            row1[i0 + h]     = o1.x * inv;  row2[i0 + h]     = o1.y * inv;
            row1[i0 + 2*h]   = o2.x * inv;  row2[i0 + 2*h]   = o2.y * inv;
            row1[i0 + 3*h]   = o3.x * inv;  row2[i0 + 3*h]   = o3.y * inv;
        }
    }
}

// ---------------------------------------------------------------------------
// K5: t[b,n,r] = sum_k y[b,k,n] * U[k,r];  out = x + t @ G^T + bu
// ---------------------------------------------------------------------------
__global__ void out_kernel(const float* __restrict__ x,
                           const float* __restrict__ y_t,
                           const float* __restrict__ U,
                           const float* __restrict__ G,
                           const float* __restrict__ bu,
                           float*       __restrict__ out) {
    __shared__ float ttile[64][R_];
    const int blk = blockIdx.x;          // 2048
    const int b   = blk >> 7;
    const int n0  = (blk & 127) << 6;
    const int t   = threadIdx.x;

    {
        const int nl = t >> 2, r = t & 3;
        const float* yb = y_t + (size_t)b * BN_ * N_ + n0 + nl;
        float s = 0.0f;
        #pragma unroll
        for (int kk = 0; kk < BN_; ++kk) s += yb[(size_t)kk * N_] * U[kk * R_ + r];
        ttile[nl][r] = s;
    }
    __syncthreads();

    float4 g = *(const float4*)(G + t * 4);
    float bv = bu[t];
    const float* xb = x   + ((size_t)b * N_ + n0) * D_;
    float*       ob = out + ((size_t)b * N_ + n0) * D_;
    for (int nl = 0; nl < 64; ++nl) {
        float t0 = ttile[nl][0], t1 = ttile[nl][1];
        float t2 = ttile[nl][2], t3 = ttile[nl][3];
        ob[nl * D_ + t] = xb[nl * D_ + t]
                        + t0 * g.x + t1 * g.y + t2 * g.z + t3 * g.w + bv;
    }
}

// ---------------------------------------------------------------------------
extern "C" void kernel_launch(void* const* d_in, const int* in_sizes, int n_in,
                              void* d_out, int out_size, void* d_ws, size_t ws_size,
                              hipStream_t stream) {
    const float* x       = (const float*)d_in[0];
    const float* coords  = (const float*)d_in[1];
    const float* Wd      = (const float*)d_in[2];
    const float* bd      = (const float*)d_in[3];
    const float* U       = (const float*)d_in[4];
    const float* V       = (const float*)d_in[5];
    const float* logit_d = (const float*)d_in[6];
    const float* Wu      = (const float*)d_in[7];
    const float* bu      = (const float*)d_in[8];
    float* out = (float*)d_out;

    char* ws = (char*)d_ws;
    int*                order  = (int*)ws;                             // 512 KB
    unsigned long long* keys   = (unsigned long long*)(ws + 512*1024); // 1 MB
    float*              G      = (float*)(ws + 1536 * 1024);           // 4 KB
    unsigned short*     wdpack = (unsigned short*)(ws + 1792 * 1024);  // 16 KB
    float*              zpk    = (float*)(ws + 2048 * 1024);           // 16 MB
    float*              zkp    = (float*)(ws + (2048 + 16384) * 1024); // 16 MB

    prep_kernel  <<<dim3(1),             dim3(256),  0, stream>>>(Wu, V, Wd, G, wdpack);
    fat_kernel   <<<dim3(2 * B_ + 1024), dim3(512),  32 * 1024, stream>>>(x, coords, wdpack, keys, zpk);
    sort2_kernel <<<dim3(2 * B_),        dim3(1024), 0, stream>>>(keys, order);
    zgather_kernel<<<dim3(B_ * 128),     dim3(512),  0, stream>>>(zpk, coords, Wd, bd, order, zkp);
    fft_filter_kernel<<<dim3(B_ * 16),   dim3(512),  64 * 1024, stream>>>(zkp, logit_d);
    out_kernel   <<<dim3(B_ * 128),      dim3(256),  0, stream>>>(x, zkp, U, G, bu, out);
}

// Round 13
// 161.206 us; speedup vs baseline: 1.0067x; 1.0067x over previous
//
#include <hip/hip_runtime.h>
#include <math.h>

#define B_    16
#define N_    8192
#define D_    256
#define BN_   32
#define R_    4
#define LOGN  13

typedef float  f32x4  __attribute__((ext_vector_type(4)));
typedef short  s16x8  __attribute__((ext_vector_type(8)));
typedef unsigned long long ull;

// ---------------------------------------------------------------------------
// Morton helpers (exact replica of reference bit-interleave)
// ---------------------------------------------------------------------------
__device__ __forceinline__ ull interleave3(ull v) {
    v = v & 2097151ULL;
    v = v | (v << 32);
    v = v & 8725724278095871ULL;
    v = v | ((v << 16) & 8725728556220671ULL);
    v = v | ((v << 8)  & 282506020581391ULL);
    v = v | ((v << 4)  & 294878547030211ULL);
    v = v | ((v << 2)  & 321685687669321ULL);
    return v;
}

__device__ __forceinline__ long long quant10(float c) {
    long long v = (long long)(c * 1023.0f);
    v = v < 0 ? 0 : (v > 1023 ? 1023 : v);
    return v;
}

__device__ __forceinline__ unsigned short f2bf(float f) {
    unsigned u = __float_as_uint(f);
    u = (u + 0x7FFF + ((u >> 16) & 1)) >> 16;   // RNE
    return (unsigned short)u;
}

__device__ __forceinline__ unsigned cvtpk_bf16(float lo, float hi) {
    unsigned r;
    asm("v_cvt_pk_bf16_f32 %0, %1, %2" : "=v"(r) : "v"(lo), "v"(hi));
    return r;
}

__device__ __forceinline__ void cswap(ull& a, ull& b, bool up) {
    ull lo = a < b ? a : b;
    ull hi = a < b ? b : a;
    a = up ? lo : hi;
    b = up ? hi : lo;
}

// ---------------------------------------------------------------------------
// P0: prep — G = Wu @ V  [256,4]  and  Wd packed to bf16 [32][256] row-major.
// ---------------------------------------------------------------------------
__global__ void prep_kernel(const float* __restrict__ Wu, const float* __restrict__ V,
                            const float* __restrict__ Wd,
                            float* __restrict__ G, unsigned short* __restrict__ wdpack) {
    const int t = threadIdx.x;   // 256
    for (int r = 0; r < R_; ++r) {
        float s = 0.0f;
        for (int kk = 0; kk < BN_; ++kk) s += Wu[t * BN_ + kk] * V[kk * R_ + r];
        G[t * R_ + r] = s;
    }
    for (int i = t; i < BN_ * 256; i += 256) {
        const int row = i >> 8, col = i & 255;
        wdpack[i] = f2bf(Wd[row * 257 + col]);
    }
}

// ---------------------------------------------------------------------------
// FAT kernel (1024 threads):
//   blocks 0..15  : FUSED-STAGE bitonic argsort of one batch (8192 keys in
//                   64 KB LDS). 3 network stages per LDS round-trip (closed
//                   8-element groups in registers) -> 33 passes total incl.
//                   morton-init sort-8 and fused order emission.
//   blocks 16..527: natural-order MFMA zraw = Wd·x, direct global->reg
//                   B-fragments, 256 rows/block (16 waves x 16 rows).
// ---------------------------------------------------------------------------
__global__ __launch_bounds__(1024)
void fat_kernel(const float* __restrict__ x,
                const float* __restrict__ coords,
                const unsigned short* __restrict__ wdpack,
                int* __restrict__ order,
                float* __restrict__ z_pk) {
    extern __shared__ ull skey[];          // 8192 * 8B = 64 KB
    const int bid = blockIdx.x;
    const int t   = threadIdx.x;

    if (bid < B_) {
        const int b = bid;
        // ---- init pass: morton keys + in-register sort-8 (sizes 2,4,8) ----
        {
            const int i0 = t * 8;
            ull K[8];
            #pragma unroll
            for (int j = 0; j < 8; ++j) {
                const float* c = coords + ((size_t)b * N_ + i0 + j) * 3;
                ull mx = interleave3((ull)quant10(c[0]));
                ull my = interleave3((ull)quant10(c[1]));
                ull mz = interleave3((ull)quant10(c[2]));
                ull m = mx | (my << 1) | (mz << 2);
                K[j] = (m << LOGN) | (ull)(i0 + j);
            }
            // size=2 (stride 1), dir = ((i&2)==0)
            cswap(K[0], K[1], true);  cswap(K[2], K[3], false);
            cswap(K[4], K[5], true);  cswap(K[6], K[7], false);
            // size=4 (strides 2,1), dir = ((i&4)==0)
            cswap(K[0], K[2], true);  cswap(K[1], K[3], true);
            cswap(K[4], K[6], false); cswap(K[5], K[7], false);
            cswap(K[0], K[1], true);  cswap(K[2], K[3], true);
            cswap(K[4], K[5], false); cswap(K[6], K[7], false);
            // size=8 (strides 4,2,1), dir = ((i0&8)==0) = t even
            const bool U = ((t & 1) == 0);
            cswap(K[0], K[4], U); cswap(K[1], K[5], U);
            cswap(K[2], K[6], U); cswap(K[3], K[7], U);
            cswap(K[0], K[2], U); cswap(K[1], K[3], U);
            cswap(K[4], K[6], U); cswap(K[5], K[7], U);
            cswap(K[0], K[1], U); cswap(K[2], K[3], U);
            cswap(K[4], K[5], U); cswap(K[6], K[7], U);
            #pragma unroll
            for (int j = 0; j < 8; ++j) skey[i0 + j] = K[j];
        }
        __syncthreads();

        // ---- phases size = 16 .. 8192, 3 stages per LDS pass ----
        for (int k = 4; k <= LOGN; ++k) {
            const int size = 1 << k;
            int s = size >> 1;
            while (s >= 4) {
                // fused-8 pass: strides s, s/2, s/4 (q = s/4)
                const int q  = s >> 2;
                const int jj = t & (q - 1);
                const int i0 = ((t - jj) << 3) + jj;   // insert 3 zero bits
                ull K[8];
                #pragma unroll
                for (int j = 0; j < 8; ++j) K[j] = skey[i0 + j * q];
                const bool up = ((i0 & size) == 0);
                cswap(K[0], K[4], up); cswap(K[1], K[5], up);
                cswap(K[2], K[6], up); cswap(K[3], K[7], up);
                cswap(K[0], K[2], up); cswap(K[1], K[3], up);
                cswap(K[4], K[6], up); cswap(K[5], K[7], up);
                cswap(K[0], K[1], up); cswap(K[2], K[3], up);
                cswap(K[4], K[5], up); cswap(K[6], K[7], up);
                #pragma unroll
                for (int j = 0; j < 8; ++j) skey[i0 + j * q] = K[j];
                __syncthreads();
                s >>= 3;
            }
            if (s == 2) {
                // fused-4 pass: strides 2,1 on consecutive quads
                #pragma unroll
                for (int u = 0; u < 2; ++u) {
                    const int i0 = (t + u * 1024) * 4;
                    ull K0 = skey[i0], K1 = skey[i0 + 1];
                    ull K2 = skey[i0 + 2], K3 = skey[i0 + 3];
                    const bool up = ((i0 & size) == 0);
                    cswap(K0, K2, up); cswap(K1, K3, up);
                    cswap(K0, K1, up); cswap(K2, K3, up);
                    skey[i0] = K0; skey[i0 + 1] = K1;
                    skey[i0 + 2] = K2; skey[i0 + 3] = K3;
                }
                __syncthreads();
            } else if (s == 1) {
                if (k == LOGN) break;   // final stride-1 fused with emit below
                #pragma unroll
                for (int u = 0; u < 4; ++u) {
                    const int i = (t + u * 1024) * 2;
                    ull a = skey[i], c = skey[i + 1];
                    cswap(a, c, ((i & size) == 0));
                    skey[i] = a; skey[i + 1] = c;
                }
                __syncthreads();
            }
        }

        // ---- final stride-1 (size=8192, all ascending) + emit order ----
        #pragma unroll
        for (int u = 0; u < 4; ++u) {
            const int i = (t + u * 1024) * 2;
            ull a = skey[i], c = skey[i + 1];
            ull lo = a < c ? a : c;
            ull hi = a < c ? c : a;
            order[b * N_ + i]     = (int)(lo & (ull)(N_ - 1));
            order[b * N_ + i + 1] = (int)(hi & (ull)(N_ - 1));
        }
    } else {
        // ===== zgemm_nat: 256 rows/block, direct global->reg fragments =====
        const int zb  = bid - B_;               // 0..511
        const int b   = zb >> 5;
        const int m0  = (zb & 31) << 8;         // 256-row tile base
        const int w   = t >> 6;                 // 0..15
        const int l   = t & 63;
        const int lg  = l >> 4;
        const int lm  = l & 15;

        s16x8 wf0[8], wf1[8];
        #pragma unroll
        for (int kc = 0; kc < 8; ++kc) {
            wf0[kc] = *(const s16x8*)(wdpack + lm * 256        + kc * 32 + lg * 8);
            wf1[kc] = *(const s16x8*)(wdpack + (lm + 16) * 256 + kc * 32 + lg * 8);
        }

        const int xr = w * 16 + lm;             // row within tile (0..255)
        const float* xrow = x + ((size_t)(b * N_ + m0 + xr)) * D_;

        f32x4 acc0 = {0.f, 0.f, 0.f, 0.f};
        f32x4 acc1 = {0.f, 0.f, 0.f, 0.f};
        #pragma unroll
        for (int kc = 0; kc < 8; ++kc) {
            const float4 va = *(const float4*)(xrow + kc * 32 + lg * 8);
            const float4 vb = *(const float4*)(xrow + kc * 32 + lg * 8 + 4);
            union { s16x8 v; unsigned u[4]; } bu_;
            bu_.u[0] = cvtpk_bf16(va.x, va.y);
            bu_.u[1] = cvtpk_bf16(va.z, va.w);
            bu_.u[2] = cvtpk_bf16(vb.x, vb.y);
            bu_.u[3] = cvtpk_bf16(vb.z, vb.w);
            acc0 = __builtin_amdgcn_mfma_f32_16x16x32_bf16(wf0[kc], bu_.v, acc0, 0, 0, 0);
            acc1 = __builtin_amdgcn_mfma_f32_16x16x32_bf16(wf1[kc], bu_.v, acc1, 0, 0, 0);
        }

        // natural-order, fully coalesced 128B-per-point store (raw)
        const int m = m0 + xr;
        float* zb_ = z_pk + ((size_t)(b * N_ + m)) * BN_;
        float4 v0, v1;
        v0.x = acc0[0]; v0.y = acc0[1]; v0.z = acc0[2]; v0.w = acc0[3];
        v1.x = acc1[0]; v1.y = acc1[1]; v1.z = acc1[2]; v1.w = acc1[3];
        *(float4*)(zb_ + lg * 4)      = v0;
        *(float4*)(zb_ + 16 + lg * 4) = v1;
    }
}

// ---------------------------------------------------------------------------
// ZG: permutation + radius + bias + relu + transpose to k-major.
// 64 sorted slots per block; reads one 128B block per point via order[p];
// writes z_kp[b][k][p] coalesced via LDS tile.
// ---------------------------------------------------------------------------
__global__ __launch_bounds__(512)
void zgather_kernel(const float* __restrict__ z_pk,
                    const float* __restrict__ coords,
                    const float* __restrict__ Wd,
                    const float* __restrict__ bd,
                    const int*   __restrict__ order,
                    float*       __restrict__ z_kp) {
    __shared__ float ltile[64][33];
    __shared__ float sWdLast[BN_];
    __shared__ float sbd[BN_];
    const int blk = blockIdx.x;           // 2048
    const int b   = blk >> 7;
    const int p0  = (blk & 127) << 6;
    const int t   = threadIdx.x;

    if (t < BN_) { sWdLast[t] = Wd[(size_t)t * 257 + 256]; sbd[t] = bd[t]; }
    __syncthreads();

    {
        const int sl = t >> 3;            // 0..63 sorted slots
        const int kc = t & 7;             // 8 float4 chunks of 32 channels
        const int p  = p0 + sl;
        const int od = order[b * N_ + p];
        float4 v = *(const float4*)(z_pk + ((size_t)(b * N_ + od)) * BN_ + kc * 4);
        const float* c = coords + ((size_t)(b * N_ + p)) * 3;
        const float rr = sqrtf(c[0] * c[0] + c[1] * c[1] + c[2] * c[2]);
        v.x = fmaxf(v.x + rr * sWdLast[kc * 4 + 0] + sbd[kc * 4 + 0], 0.0f);
        v.y = fmaxf(v.y + rr * sWdLast[kc * 4 + 1] + sbd[kc * 4 + 1], 0.0f);
        v.z = fmaxf(v.z + rr * sWdLast[kc * 4 + 2] + sbd[kc * 4 + 2], 0.0f);
        v.w = fmaxf(v.w + rr * sWdLast[kc * 4 + 3] + sbd[kc * 4 + 3], 0.0f);
        ltile[sl][kc * 4 + 0] = v.x;
        ltile[sl][kc * 4 + 1] = v.y;
        ltile[sl][kc * 4 + 2] = v.z;
        ltile[sl][kc * 4 + 3] = v.w;
    }
    __syncthreads();

    {
        const int k  = t >> 4;            // 0..31
        const int pc = t & 15;            // 16 x float4 along p
        float4 o;
        o.x = ltile[pc * 4 + 0][k];
        o.y = ltile[pc * 4 + 1][k];
        o.z = ltile[pc * 4 + 2][k];
        o.w = ltile[pc * 4 + 3][k];
        *(float4*)(z_kp + (size_t)(b * BN_ + k) * N_ + p0 + pc * 4) = o;
    }
}

// ---------------------------------------------------------------------------
// K4: PAIR-PACKED spectral filter (proven round-7/9/11 version, no swizzle).
// ---------------------------------------------------------------------------
__device__ __forceinline__ float2 cmul(float2 a, float2 b) {
    return make_float2(a.x * b.x - a.y * b.y, a.x * b.y + a.y * b.x);
}
__device__ __forceinline__ float2 sdmix(float S, float D, float2 P, float2 Q) {
    return make_float2(S * P.x + D * Q.x, S * P.y - D * Q.y);
}

__global__ __launch_bounds__(512)
void fft_filter_kernel(float* __restrict__ zy,
                       const float* __restrict__ logit_d) {
    extern __shared__ float2 cbuf[];   // 64 KB

    const int bk = blockIdx.x;     // 256 = B_ * 16
    const int b  = bk >> 4;
    const int kp = bk & 15;
    const int t  = threadIdx.x;

    float* row1 = zy + (size_t)(b * BN_ + 2 * kp) * N_;
    float* row2 = row1 + N_;

    float d1 = fminf(fmaxf(logit_d[2 * kp],     -10.0f), 10.0f);
    float d2 = fminf(fmaxf(logit_d[2 * kp + 1], -10.0f), 10.0f);

    const float cpi  = 3.14159265358979323846f;
    const float c2pi = 6.28318530717958647692f;
    const float A    = c2pi * 8192.0f / 8191.0f;

    const float Eh1 = __expf(-0.5f * A * d1), E1 = Eh1 * Eh1;
    const float Eh2 = __expf(-0.5f * A * d2), E2 = Eh2 * Eh2;

    {
        const int h = 4096, hh = 2048;
        #pragma unroll
        for (int u = 0; u < 4; ++u) {
            const int i0 = t + u * 512;
            float2 c0 = make_float2(row1[i0],            row2[i0]);
            float2 c1 = make_float2(row1[i0 + hh],       row2[i0 + hh]);
            float2 c2 = make_float2(row1[i0 + h],        row2[i0 + h]);
            float2 c3 = make_float2(row1[i0 + h + hh],   row2[i0 + h + hh]);
            float sA, cA;
            __sincosf(-cpi * (float)i0 / (float)h, &sA, &cA);
            const float2 twA1 = make_float2(cA, sA);
            const float2 twA2 = make_float2(sA, -cA);
            const float2 twB  = make_float2(2.0f * cA * cA - 1.0f, 2.0f * sA * cA);
            float2 a0 = make_float2(c0.x + c2.x, c0.y + c2.y);
            float2 a1 = make_float2(c1.x + c3.x, c1.y + c3.y);
            float2 b0 = cmul(make_float2(c0.x - c2.x, c0.y - c2.y), twA1);
            float2 b1 = cmul(make_float2(c1.x - c3.x, c1.y - c3.y), twA2);
            cbuf[i0]          = make_float2(a0.x + a1.x, a0.y + a1.y);
            cbuf[i0 + hh]     = cmul(make_float2(a0.x - a1.x, a0.y - a1.y), twB);
            cbuf[i0 + h]      = make_float2(b0.x + b1.x, b0.y + b1.y);
            cbuf[i0 + h + hh] = cmul(make_float2(b0.x - b1.x, b0.y - b1.y), twB);
        }
        __syncthreads();
    }

    #pragma unroll
    for (int h = 1024; h >= 4; h >>= 2) {
        const int hh = h >> 1;
        #pragma unroll
        for (int u = 0; u < 4; ++u) {
            const int q   = t + u * 512;
            const int jj  = q & (hh - 1);
            const int i0  = ((q - jj) << 2) + jj;
            float2 c0 = cbuf[i0];
            float2 c1 = cbuf[i0 + hh];
            float2 c2 = cbuf[i0 + h];
            float2 c3 = cbuf[i0 + h + hh];
            float sA, cA;
            __sincosf(-cpi * (float)jj / (float)h, &sA, &cA);
            const float2 twA1 = make_float2(cA, sA);
            const float2 twA2 = make_float2(sA, -cA);
            const float2 twB  = make_float2(2.0f * cA * cA - 1.0f, 2.0f * sA * cA);
            float2 a0 = make_float2(c0.x + c2.x, c0.y + c2.y);
            float2 a1 = make_float2(c1.x + c3.x, c1.y + c3.y);
            float2 b0 = cmul(make_float2(c0.x - c2.x, c0.y - c2.y), twA1);
            float2 b1 = cmul(make_float2(c1.x - c3.x, c1.y - c3.y), twA2);
            cbuf[i0]          = make_float2(a0.x + a1.x, a0.y + a1.y);
            cbuf[i0 + hh]     = cmul(make_float2(a0.x - a1.x, a0.y - a1.y), twB);
            cbuf[i0 + h]      = make_float2(b0.x + b1.x, b0.y + b1.y);
            cbuf[i0 + h + hh] = cmul(make_float2(b0.x - b1.x, b0.y - b1.y), twB);
        }
        __syncthreads();
    }

    {
        #pragma unroll
        for (int v = 0; v < 4; ++v) {
            const int u = t + v * 512;
            if (u == 0) {
                {
                    float2 g0 = cbuf[0], g1 = cbuf[1];
                    float2 Pa = make_float2(g0.x + g1.x, g0.y + g1.y);
                    float2 Pb = make_float2(g0.x - g1.x, g0.y - g1.y);
                    float2 Ra = Pa;
                    float Sb = 0.5f * (Eh1 + Eh2), Db = 0.5f * (Eh1 - Eh2);
                    float2 Rb = sdmix(Sb, Db, Pb, Pb);
                    cbuf[0] = make_float2(Ra.x + Rb.x, Ra.y + Rb.y);
                    cbuf[1] = make_float2(Ra.x - Rb.x, Ra.y - Rb.y);
                }
                {
                    float wu = c2pi * 2048.0f / 8191.0f;
                    float h1 = __expf(-wu * d1), h2 = __expf(-wu * d2);
                    float h1b = h1 * Eh1, h2b = h2 * Eh2;
                    float Hs1a = 0.5f * (h1 + E1 / h1);
                    float Hs2a = 0.5f * (h2 + E2 / h2);
                    float Hs1b = 0.5f * (h1b + E1 / h1b);
                    float Hs2b = 0.5f * (h2b + E2 / h2b);
                    float Sa = 0.5f * (Hs1a + Hs2a), Da = 0.5f * (Hs1a - Hs2a);
                    float Sb = 0.5f * (Hs1b + Hs2b), Db = 0.5f * (Hs1b - Hs2b);
                    float2 g0 = cbuf[2], g1 = cbuf[3];
                    float2 Pa = make_float2(g0.x + g1.x, g0.y + g1.y);
                    float2 Pb = make_float2(g0.x - g1.x, g0.y - g1.y);
                    float2 Ra = sdmix(Sa, Da, Pa, Pb);
                    float2 Rb = sdmix(Sb, Db, Pb, Pa);
                    cbuf[2] = make_float2(Ra.x + Rb.x, Ra.y + Rb.y);
                    cbuf[3] = make_float2(Ra.x - Rb.x, Ra.y - Rb.y);
                }
            } else {
                const int u2 = 4096 - u;
                const int c  = (int)(__brev((unsigned)u)  >> 20);
                const int c2 = (int)(__brev((unsigned)u2) >> 20);
                float2 g0 = cbuf[2 * c],  g1 = cbuf[2 * c + 1];
                float2 q0 = cbuf[2 * c2], q1 = cbuf[2 * c2 + 1];
                float2 Pa  = make_float2(g0.x + g1.x, g0.y + g1.y);
                float2 Pb  = make_float2(g0.x - g1.x, g0.y - g1.y);
                float2 Pa2 = make_float2(q0.x + q1.x, q0.y + q1.y);
                float2 Pb2 = make_float2(q0.x - q1.x, q0.y - q1.y);
                float wu = c2pi * (float)u / 8191.0f;
                float h1 = __expf(-wu * d1), h2 = __expf(-wu * d2);
                float h1b = h1 * Eh1, h2b = h2 * Eh2;
                float Hs1a = 0.5f * (h1 + E1 / h1);
                float Hs2a = 0.5f * (h2 + E2 / h2);
                float Hs1b = 0.5f * (h1b + E1 / h1b);
                float Hs2b = 0.5f * (h2b + E2 / h2b);
                float Sa = 0.5f * (Hs1a + Hs2a), Da = 0.5f * (Hs1a - Hs2a);
                float Sb = 0.5f * (Hs1b + Hs2b), Db = 0.5f * (Hs1b - Hs2b);
                float2 Ra  = sdmix(Sa, Da, Pa,  Pb2);
                float2 Rb2 = sdmix(Sa, Da, Pb2, Pa);
                float2 Rb  = sdmix(Sb, Db, Pb,  Pa2);
                float2 Ra2 = sdmix(Sb, Db, Pa2, Pb);
                cbuf[2 * c]      = make_float2(Ra.x + Rb.x,   Ra.y + Rb.y);
                cbuf[2 * c + 1]  = make_float2(Ra.x - Rb.x,   Ra.y - Rb.y);
                cbuf[2 * c2]     = make_float2(Ra2.x + Rb2.x, Ra2.y + Rb2.y);
                cbuf[2 * c2 + 1] = make_float2(Ra2.x - Rb2.x, Ra2.y - Rb2.y);
            }
        }
        __syncthreads();
    }

    #pragma unroll
    for (int h = 2; h <= 512; h <<= 2) {
        #pragma unroll
        for (int u = 0; u < 4; ++u) {
            const int q  = t + u * 512;
            const int jj = q & (h - 1);
            const int i0 = ((q - jj) << 2) + jj;
            float2 c0 = cbuf[i0];
            float2 c1 = cbuf[i0 + h];
            float2 c2 = cbuf[i0 + 2 * h];
            float2 c3 = cbuf[i0 + 3 * h];
            float sa, ca;
            __sincosf(cpi * (float)jj / (float)(2 * h), &sa, &ca);
            const float2 tw1  = make_float2(2.0f * ca * ca - 1.0f, 2.0f * sa * ca);
            const float2 tw2a = make_float2(ca, sa);
            const float2 tw2b = make_float2(-sa, ca);
            float2 t0 = cmul(c1, tw1);
            float2 a0 = make_float2(c0.x + t0.x, c0.y + t0.y);
            float2 a1 = make_float2(c0.x - t0.x, c0.y - t0.y);
            float2 t1 = cmul(c3, tw1);
            float2 b0 = make_float2(c2.x + t1.x, c2.y + t1.y);
            float2 b1 = make_float2(c2.x - t1.x, c2.y - t1.y);
            float2 t2 = cmul(b0, tw2a);
            cbuf[i0]         = make_float2(a0.x + t2.x, a0.y + t2.y);
            cbuf[i0 + 2 * h] = make_float2(a0.x - t2.x, a0.y - t2.y);
            float2 t3 = cmul(b1, tw2b);
            cbuf[i0 + h]     = make_float2(a1.x + t3.x, a1.y + t3.y);
            cbuf[i0 + 3 * h] = make_float2(a1.x - t3.x, a1.y - t3.y);
        }
        __syncthreads();
    }

    {
        const int h = 2048;
        const float inv = 1.0f / (float)N_;
        #pragma unroll
        for (int u = 0; u < 4; ++u) {
            const int jj = t + u * 512;
            const int i0 = jj;
            float2 c0 = cbuf[i0];
            float2 c1 = cbuf[i0 + h];
            float2 c2 = cbuf[i0 + 2 * h];
            float2 c3 = cbuf[i0 + 3 * h];
            float sa, ca;
            __sincosf(cpi * (float)jj / (float)(2 * h), &sa, &ca);
            const float2 tw1  = make_float2(2.0f * ca * ca - 1.0f, 2.0f * sa * ca);
            const float2 tw2a = make_float2(ca, sa);
            const float2 tw2b = make_float2(-sa, ca);
            float2 t0 = cmul(c1, tw1);
            float2 a0 = make_float2(c0.x + t0.x, c0.y + t0.y);
            float2 a1 = make_float2(c0.x - t0.x, c0.y - t0.y);
            float2 t1 = cmul(c3, tw1);
            float2 b0 = make_float2(c2.x + t1.x, c2.y + t1.y);
            float2 b1 = make_float2(c2.x - t1.x, c2.y - t1.y);
            float2 t2 = cmul(b0, tw2a);
            float2 o0 = make_float2(a0.x + t2.x, a0.y + t2.y);
            float2 o2 = make_float2(a0.x - t2.x, a0.y - t2.y);
            float2 t3 = cmul(b1, tw2b);
            float2 o1 = make_float2(a1.x + t3.x, a1.y + t3.y);
            float2 o3 = make_float2(a1.x - t3.x, a1.y - t3.y);
            row1[i0]         = o0.x * inv;  row2[i0]         = o0.y * inv;
            row1[i0 + h]     = o1.x * inv;  row2[i0 + h]     = o1.y * inv;
            row1[i0 + 2*h]   = o2.x * inv;  row2[i0 + 2*h]   = o2.y * inv;
            row1[i0 + 3*h]   = o3.x * inv;  row2[i0 + 3*h]   = o3.y * inv;
        }
    }
}

// ---------------------------------------------------------------------------
// K5: t[b,n,r] = sum_k y[b,k,n] * U[k,r];  out = x + t @ G^T + bu
// ---------------------------------------------------------------------------
__global__ void out_kernel(const float* __restrict__ x,
                           const float* __restrict__ y_t,
                           const float* __restrict__ U,
                           const float* __restrict__ G,
                           const float* __restrict__ bu,
                           float*       __restrict__ out) {
    __shared__ float ttile[64][R_];
    const int blk = blockIdx.x;          // 2048
    const int b   = blk >> 7;
    const int n0  = (blk & 127) << 6;
    const int t   = threadIdx.x;

    {
        const int nl = t >> 2, r = t & 3;
        const float* yb = y_t + (size_t)b * BN_ * N_ + n0 + nl;
        float s = 0.0f;
        #pragma unroll
        for (int kk = 0; kk < BN_; ++kk) s += yb[(size_t)kk * N_] * U[kk * R_ + r];
        ttile[nl][r] = s;
    }
    __syncthreads();

    float4 g = *(const float4*)(G + t * 4);
    float bv = bu[t];
    const float* xb = x   + ((size_t)b * N_ + n0) * D_;
    float*       ob = out + ((size_t)b * N_ + n0) * D_;
    for (int nl = 0; nl < 64; ++nl) {
        float t0 = ttile[nl][0], t1 = ttile[nl][1];
        float t2 = ttile[nl][2], t3 = ttile[nl][3];
        ob[nl * D_ + t] = xb[nl * D_ + t]
                        + t0 * g.x + t1 * g.y + t2 * g.z + t3 * g.w + bv;
    }
}

// ---------------------------------------------------------------------------
extern "C" void kernel_launch(void* const* d_in, const int* in_sizes, int n_in,
                              void* d_out, int out_size, void* d_ws, size_t ws_size,
                              hipStream_t stream) {
    const float* x       = (const float*)d_in[0];
    const float* coords  = (const float*)d_in[1];
    const float* Wd      = (const float*)d_in[2];
    const float* bd      = (const float*)d_in[3];
    const float* U       = (const float*)d_in[4];
    const float* V       = (const float*)d_in[5];
    const float* logit_d = (const float*)d_in[6];
    const float* Wu      = (const float*)d_in[7];
    const float* bu      = (const float*)d_in[8];
    float* out = (float*)d_out;

    char* ws = (char*)d_ws;
    int*            order  = (int*)ws;                             // 512 KB
    float*          G      = (float*)(ws + 1536 * 1024);           // 4 KB
    unsigned short* wdpack = (unsigned short*)(ws + 1792 * 1024);  // 16 KB
    float*          zpk    = (float*)(ws + 2048 * 1024);           // 16 MB
    float*          zkp    = (float*)(ws + (2048 + 16384) * 1024); // 16 MB

    prep_kernel  <<<dim3(1),          dim3(256),  0, stream>>>(Wu, V, Wd, G, wdpack);
    fat_kernel   <<<dim3(B_ + 512),   dim3(1024), 64 * 1024, stream>>>(x, coords, wdpack, order, zpk);
    zgather_kernel<<<dim3(B_ * 128),  dim3(512),  0, stream>>>(zpk, coords, Wd, bd, order, zkp);
    fft_filter_kernel<<<dim3(B_ * 16), dim3(512), 64 * 1024, stream>>>(zkp, logit_d);
    out_kernel   <<<dim3(B_ * 128),   dim3(256),  0, stream>>>(x, zkp, U, G, bu, out);
}

// Round 14
// 148.669 us; speedup vs baseline: 1.0916x; 1.0843x over previous
//
#include <hip/hip_runtime.h>
#include <math.h>

#define B_    16
#define N_    8192
#define D_    256
#define BN_   32
#define R_    4
#define LOGN  13

typedef float  f32x4  __attribute__((ext_vector_type(4)));
typedef short  s16x8  __attribute__((ext_vector_type(8)));
typedef unsigned long long ull;
typedef ull    ull2   __attribute__((ext_vector_type(2)));

// ---------------------------------------------------------------------------
// Morton helpers (exact replica of reference bit-interleave)
// ---------------------------------------------------------------------------
__device__ __forceinline__ ull interleave3(ull v) {
    v = v & 2097151ULL;
    v = v | (v << 32);
    v = v & 8725724278095871ULL;
    v = v | ((v << 16) & 8725728556220671ULL);
    v = v | ((v << 8)  & 282506020581391ULL);
    v = v | ((v << 4)  & 294878547030211ULL);
    v = v | ((v << 2)  & 321685687669321ULL);
    return v;
}

__device__ __forceinline__ long long quant10(float c) {
    long long v = (long long)(c * 1023.0f);
    v = v < 0 ? 0 : (v > 1023 ? 1023 : v);
    return v;
}

__device__ __forceinline__ unsigned short f2bf(float f) {
    unsigned u = __float_as_uint(f);
    u = (u + 0x7FFF + ((u >> 16) & 1)) >> 16;   // RNE
    return (unsigned short)u;
}

__device__ __forceinline__ unsigned cvtpk_bf16(float lo, float hi) {
    unsigned r;
    asm("v_cvt_pk_bf16_f32 %0, %1, %2" : "=v"(r) : "v"(lo), "v"(hi));
    return r;
}

__device__ __forceinline__ void cswap(ull& a, ull& b, bool up) {
    ull lo = a < b ? a : b;
    ull hi = a < b ? b : a;
    a = up ? lo : hi;
    b = up ? hi : lo;
}

// ---------------------------------------------------------------------------
// P0: prep — G = Wu @ V  [256,4]  and  Wd packed to bf16 [32][256] row-major.
// ---------------------------------------------------------------------------
__global__ void prep_kernel(const float* __restrict__ Wu, const float* __restrict__ V,
                            const float* __restrict__ Wd,
                            float* __restrict__ G, unsigned short* __restrict__ wdpack) {
    const int t = threadIdx.x;   // 256
    for (int r = 0; r < R_; ++r) {
        float s = 0.0f;
        for (int kk = 0; kk < BN_; ++kk) s += Wu[t * BN_ + kk] * V[kk * R_ + r];
        G[t * R_ + r] = s;
    }
    for (int i = t; i < BN_ * 256; i += 256) {
        const int row = i >> 8, col = i & 255;
        wdpack[i] = f2bf(Wd[row * 257 + col]);
    }
}

// ---------------------------------------------------------------------------
// FAT kernel (1024 threads):
//   blocks 0..15  : fused-stage bitonic argsort of one batch (8192 keys,
//                   64 KB LDS) with CONFLICT-FREE pass shapes:
//                   TRIPLE (q>=8), DOUBLE{16,8}, SINGLE{8}, CONTIG{4,2,1}
//                   via b128. All passes <=2-way bank aliasing.
//   blocks 16..527: natural-order MFMA zraw = Wd·x, direct global->reg
//                   B-fragments, 256 rows/block (16 waves x 16 rows).
// ---------------------------------------------------------------------------
__global__ __launch_bounds__(1024)
void fat_kernel(const float* __restrict__ x,
                const float* __restrict__ coords,
                const unsigned short* __restrict__ wdpack,
                int* __restrict__ order,
                float* __restrict__ z_pk) {
    extern __shared__ ull skey[];          // 8192 * 8B = 64 KB
    const int bid = blockIdx.x;
    const int t   = threadIdx.x;

    if (bid < B_) {
        const int b = bid;
        // ---- init pass: morton keys + in-register sort-8 (sizes 2,4,8) ----
        {
            const int i0 = t * 8;
            ull K[8];
            #pragma unroll
            for (int j = 0; j < 8; ++j) {
                const float* c = coords + ((size_t)b * N_ + i0 + j) * 3;
                ull mx = interleave3((ull)quant10(c[0]));
                ull my = interleave3((ull)quant10(c[1]));
                ull mz = interleave3((ull)quant10(c[2]));
                ull m = mx | (my << 1) | (mz << 2);
                K[j] = (m << LOGN) | (ull)(i0 + j);
            }
            // size=2
            cswap(K[0], K[1], true);  cswap(K[2], K[3], false);
            cswap(K[4], K[5], true);  cswap(K[6], K[7], false);
            // size=4
            cswap(K[0], K[2], true);  cswap(K[1], K[3], true);
            cswap(K[4], K[6], false); cswap(K[5], K[7], false);
            cswap(K[0], K[1], true);  cswap(K[2], K[3], true);
            cswap(K[4], K[5], false); cswap(K[6], K[7], false);
            // size=8
            const bool U = ((t & 1) == 0);
            cswap(K[0], K[4], U); cswap(K[1], K[5], U);
            cswap(K[2], K[6], U); cswap(K[3], K[7], U);
            cswap(K[0], K[2], U); cswap(K[1], K[3], U);
            cswap(K[4], K[6], U); cswap(K[5], K[7], U);
            cswap(K[0], K[1], U); cswap(K[2], K[3], U);
            cswap(K[4], K[5], U); cswap(K[6], K[7], U);
            ull2* p2 = (ull2*)&skey[i0];
            #pragma unroll
            for (int j = 0; j < 4; ++j) { ull2 w; w.x = K[2*j]; w.y = K[2*j+1]; p2[j] = w; }
        }
        __syncthreads();

        // ---- phases size = 16 .. 8192 ----
        for (int k = 4; k <= LOGN; ++k) {
            const int size = 1 << k;
            int s = size >> 1;

            // TRIPLE passes: strides {s, s/2, s/4}, q = s/4 >= 8 (conflict-free)
            while (s >= 32) {
                const int q  = s >> 2;
                const int jj = t & (q - 1);
                const int i0 = ((t - jj) << 3) + jj;
                ull K[8];
                #pragma unroll
                for (int j = 0; j < 8; ++j) K[j] = skey[i0 + j * q];
                const bool up = ((i0 & size) == 0);
                cswap(K[0], K[4], up); cswap(K[1], K[5], up);
                cswap(K[2], K[6], up); cswap(K[3], K[7], up);
                cswap(K[0], K[2], up); cswap(K[1], K[3], up);
                cswap(K[4], K[6], up); cswap(K[5], K[7], up);
                cswap(K[0], K[1], up); cswap(K[2], K[3], up);
                cswap(K[4], K[5], up); cswap(K[6], K[7], up);
                #pragma unroll
                for (int j = 0; j < 8; ++j) skey[i0 + j * q] = K[j];
                __syncthreads();
                s >>= 3;
            }

            if (s == 16) {
                // DOUBLE pass: strides {16, 8}
                #pragma unroll
                for (int u = 0; u < 2; ++u) {
                    const int p  = t + u * 1024;          // 2048 groups of 4
                    const int jj = p & 7;
                    const int i0 = ((p - jj) << 2) + jj;
                    ull K0 = skey[i0], K1 = skey[i0 + 8];
                    ull K2 = skey[i0 + 16], K3 = skey[i0 + 24];
                    const bool up = ((i0 & size) == 0);
                    cswap(K0, K2, up); cswap(K1, K3, up);   // stride 16
                    cswap(K0, K1, up); cswap(K2, K3, up);   // stride 8
                    skey[i0] = K0; skey[i0 + 8] = K1;
                    skey[i0 + 16] = K2; skey[i0 + 24] = K3;
                }
                __syncthreads();
            } else if (s == 8) {
                // SINGLE pass: stride 8
                #pragma unroll
                for (int u = 0; u < 4; ++u) {
                    const int p  = t + u * 1024;          // 4096 pairs
                    const int jj = p & 7;
                    const int i  = ((p - jj) << 1) + jj;
                    ull a = skey[i], c = skey[i + 8];
                    cswap(a, c, ((i & size) == 0));
                    skey[i] = a; skey[i + 8] = c;
                }
                __syncthreads();
            }
            // else s == 4: fall straight to CONTIG

            // CONTIG pass: strides {4,2,1} on thread-owned 8 consecutive (b128 I/O)
            {
                const int i0 = t * 8;
                ull K[8];
                ull2* p2 = (ull2*)&skey[i0];
                #pragma unroll
                for (int j = 0; j < 4; ++j) { ull2 w = p2[j]; K[2*j] = w.x; K[2*j+1] = w.y; }
                const bool up = ((i0 & size) == 0);
                cswap(K[0], K[4], up); cswap(K[1], K[5], up);
                cswap(K[2], K[6], up); cswap(K[3], K[7], up);
                cswap(K[0], K[2], up); cswap(K[1], K[3], up);
                cswap(K[4], K[6], up); cswap(K[5], K[7], up);
                cswap(K[0], K[1], up); cswap(K[2], K[3], up);
                cswap(K[4], K[5], up); cswap(K[6], K[7], up);
                if (k == LOGN) {
                    // final phase: emit order directly (all ascending)
                    #pragma unroll
                    for (int j = 0; j < 8; ++j)
                        order[b * N_ + i0 + j] = (int)(K[j] & (ull)(N_ - 1));
                } else {
                    #pragma unroll
                    for (int j = 0; j < 4; ++j) { ull2 w; w.x = K[2*j]; w.y = K[2*j+1]; p2[j] = w; }
                    __syncthreads();
                }
            }
        }
    } else {
        // ===== zgemm_nat: 256 rows/block, direct global->reg fragments =====
        const int zb  = bid - B_;               // 0..511
        const int b   = zb >> 5;
        const int m0  = (zb & 31) << 8;         // 256-row tile base
        const int w   = t >> 6;                 // 0..15
        const int l   = t & 63;
        const int lg  = l >> 4;
        const int lm  = l & 15;

        s16x8 wf0[8], wf1[8];
        #pragma unroll
        for (int kc = 0; kc < 8; ++kc) {
            wf0[kc] = *(const s16x8*)(wdpack + lm * 256        + kc * 32 + lg * 8);
            wf1[kc] = *(const s16x8*)(wdpack + (lm + 16) * 256 + kc * 32 + lg * 8);
        }

        const int xr = w * 16 + lm;             // row within tile (0..255)
        const float* xrow = x + ((size_t)(b * N_ + m0 + xr)) * D_;

        f32x4 acc0 = {0.f, 0.f, 0.f, 0.f};
        f32x4 acc1 = {0.f, 0.f, 0.f, 0.f};
        #pragma unroll
        for (int kc = 0; kc < 8; ++kc) {
            const float4 va = *(const float4*)(xrow + kc * 32 + lg * 8);
            const float4 vb = *(const float4*)(xrow + kc * 32 + lg * 8 + 4);
            union { s16x8 v; unsigned u[4]; } bu_;
            bu_.u[0] = cvtpk_bf16(va.x, va.y);
            bu_.u[1] = cvtpk_bf16(va.z, va.w);
            bu_.u[2] = cvtpk_bf16(vb.x, vb.y);
            bu_.u[3] = cvtpk_bf16(vb.z, vb.w);
            acc0 = __builtin_amdgcn_mfma_f32_16x16x32_bf16(wf0[kc], bu_.v, acc0, 0, 0, 0);
            acc1 = __builtin_amdgcn_mfma_f32_16x16x32_bf16(wf1[kc], bu_.v, acc1, 0, 0, 0);
        }

        // natural-order, fully coalesced 128B-per-point store (raw)
        const int m = m0 + xr;
        float* zb_ = z_pk + ((size_t)(b * N_ + m)) * BN_;
        float4 v0, v1;
        v0.x = acc0[0]; v0.y = acc0[1]; v0.z = acc0[2]; v0.w = acc0[3];
        v1.x = acc1[0]; v1.y = acc1[1]; v1.z = acc1[2]; v1.w = acc1[3];
        *(float4*)(zb_ + lg * 4)      = v0;
        *(float4*)(zb_ + 16 + lg * 4) = v1;
    }
}

// ---------------------------------------------------------------------------
// ZG: permutation + radius + bias + relu + transpose to k-major.
// ---------------------------------------------------------------------------
__global__ __launch_bounds__(512)
void zgather_kernel(const float* __restrict__ z_pk,
                    const float* __restrict__ coords,
                    const float* __restrict__ Wd,
                    const float* __restrict__ bd,
                    const int*   __restrict__ order,
                    float*       __restrict__ z_kp) {
    __shared__ float ltile[64][33];
    __shared__ float sWdLast[BN_];
    __shared__ float sbd[BN_];
    const int blk = blockIdx.x;           // 2048
    const int b   = blk >> 7;
    const int p0  = (blk & 127) << 6;
    const int t   = threadIdx.x;

    if (t < BN_) { sWdLast[t] = Wd[(size_t)t * 257 + 256]; sbd[t] = bd[t]; }
    __syncthreads();

    {
        const int sl = t >> 3;            // 0..63 sorted slots
        const int kc = t & 7;             // 8 float4 chunks of 32 channels
        const int p  = p0 + sl;
        const int od = order[b * N_ + p];
        float4 v = *(const float4*)(z_pk + ((size_t)(b * N_ + od)) * BN_ + kc * 4);
        const float* c = coords + ((size_t)(b * N_ + p)) * 3;
        const float rr = sqrtf(c[0] * c[0] + c[1] * c[1] + c[2] * c[2]);
        v.x = fmaxf(v.x + rr * sWdLast[kc * 4 + 0] + sbd[kc * 4 + 0], 0.0f);
        v.y = fmaxf(v.y + rr * sWdLast[kc * 4 + 1] + sbd[kc * 4 + 1], 0.0f);
        v.z = fmaxf(v.z + rr * sWdLast[kc * 4 + 2] + sbd[kc * 4 + 2], 0.0f);
        v.w = fmaxf(v.w + rr * sWdLast[kc * 4 + 3] + sbd[kc * 4 + 3], 0.0f);
        ltile[sl][kc * 4 + 0] = v.x;
        ltile[sl][kc * 4 + 1] = v.y;
        ltile[sl][kc * 4 + 2] = v.z;
        ltile[sl][kc * 4 + 3] = v.w;
    }
    __syncthreads();

    {
        const int k  = t >> 4;            // 0..31
        const int pc = t & 15;            // 16 x float4 along p
        float4 o;
        o.x = ltile[pc * 4 + 0][k];
        o.y = ltile[pc * 4 + 1][k];
        o.z = ltile[pc * 4 + 2][k];
        o.w = ltile[pc * 4 + 3][k];
        *(float4*)(z_kp + (size_t)(b * BN_ + k) * N_ + p0 + pc * 4) = o;
    }
}

// ---------------------------------------------------------------------------
// K4: PAIR-PACKED spectral filter (proven round-7/9/11 version).
// ---------------------------------------------------------------------------
__device__ __forceinline__ float2 cmul(float2 a, float2 b) {
    return make_float2(a.x * b.x - a.y * b.y, a.x * b.y + a.y * b.x);
}
__device__ __forceinline__ float2 sdmix(float S, float D, float2 P, float2 Q) {
    return make_float2(S * P.x + D * Q.x, S * P.y - D * Q.y);
}

__global__ __launch_bounds__(512)
void fft_filter_kernel(float* __restrict__ zy,
                       const float* __restrict__ logit_d) {
    extern __shared__ float2 cbuf[];   // 64 KB

    const int bk = blockIdx.x;     // 256 = B_ * 16
    const int b  = bk >> 4;
    const int kp = bk & 15;
    const int t  = threadIdx.x;

    float* row1 = zy + (size_t)(b * BN_ + 2 * kp) * N_;
    float* row2 = row1 + N_;

    float d1 = fminf(fmaxf(logit_d[2 * kp],     -10.0f), 10.0f);
    float d2 = fminf(fmaxf(logit_d[2 * kp + 1], -10.0f), 10.0f);

    const float cpi  = 3.14159265358979323846f;
    const float c2pi = 6.28318530717958647692f;
    const float A    = c2pi * 8192.0f / 8191.0f;

    const float Eh1 = __expf(-0.5f * A * d1), E1 = Eh1 * Eh1;
    const float Eh2 = __expf(-0.5f * A * d2), E2 = Eh2 * Eh2;

    {
        const int h = 4096, hh = 2048;
        #pragma unroll
        for (int u = 0; u < 4; ++u) {
            const int i0 = t + u * 512;
            float2 c0 = make_float2(row1[i0],            row2[i0]);
            float2 c1 = make_float2(row1[i0 + hh],       row2[i0 + hh]);
            float2 c2 = make_float2(row1[i0 + h],        row2[i0 + h]);
            float2 c3 = make_float2(row1[i0 + h + hh],   row2[i0 + h + hh]);
            float sA, cA;
            __sincosf(-cpi * (float)i0 / (float)h, &sA, &cA);
            const float2 twA1 = make_float2(cA, sA);
            const float2 twA2 = make_float2(sA, -cA);
            const float2 twB  = make_float2(2.0f * cA * cA - 1.0f, 2.0f * sA * cA);
            float2 a0 = make_float2(c0.x + c2.x, c0.y + c2.y);
            float2 a1 = make_float2(c1.x + c3.x, c1.y + c3.y);
            float2 b0 = cmul(make_float2(c0.x - c2.x, c0.y - c2.y), twA1);
            float2 b1 = cmul(make_float2(c1.x - c3.x, c1.y - c3.y), twA2);
            cbuf[i0]          = make_float2(a0.x + a1.x, a0.y + a1.y);
            cbuf[i0 + hh]     = cmul(make_float2(a0.x - a1.x, a0.y - a1.y), twB);
            cbuf[i0 + h]      = make_float2(b0.x + b1.x, b0.y + b1.y);
            cbuf[i0 + h + hh] = cmul(make_float2(b0.x - b1.x, b0.y - b1.y), twB);
        }
        __syncthreads();
    }

    #pragma unroll
    for (int h = 1024; h >= 4; h >>= 2) {
        const int hh = h >> 1;
        #pragma unroll
        for (int u = 0; u < 4; ++u) {
            const int q   = t + u * 512;
            const int jj  = q & (hh - 1);
            const int i0  = ((q - jj) << 2) + jj;
            float2 c0 = cbuf[i0];
            float2 c1 = cbuf[i0 + hh];
            float2 c2 = cbuf[i0 + h];
            float2 c3 = cbuf[i0 + h + hh];
            float sA, cA;
            __sincosf(-cpi * (float)jj / (float)h, &sA, &cA);
            const float2 twA1 = make_float2(cA, sA);
            const float2 twA2 = make_float2(sA, -cA);
            const float2 twB  = make_float2(2.0f * cA * cA - 1.0f, 2.0f * sA * cA);
            float2 a0 = make_float2(c0.x + c2.x, c0.y + c2.y);
            float2 a1 = make_float2(c1.x + c3.x, c1.y + c3.y);
            float2 b0 = cmul(make_float2(c0.x - c2.x, c0.y - c2.y), twA1);
            float2 b1 = cmul(make_float2(c1.x - c3.x, c1.y - c3.y), twA2);
            cbuf[i0]          = make_float2(a0.x + a1.x, a0.y + a1.y);
            cbuf[i0 + hh]     = cmul(make_float2(a0.x - a1.x, a0.y - a1.y), twB);
            cbuf[i0 + h]      = make_float2(b0.x + b1.x, b0.y + b1.y);
            cbuf[i0 + h + hh] = cmul(make_float2(b0.x - b1.x, b0.y - b1.y), twB);
        }
        __syncthreads();
    }

    {
        #pragma unroll
        for (int v = 0; v < 4; ++v) {
            const int u = t + v * 512;
            if (u == 0) {
                {
                    float2 g0 = cbuf[0], g1 = cbuf[1];
                    float2 Pa = make_float2(g0.x + g1.x, g0.y + g1.y);
                    float2 Pb = make_float2(g0.x - g1.x, g0.y - g1.y);
                    float2 Ra = Pa;
                    float Sb = 0.5f * (Eh1 + Eh2), Db = 0.5f * (Eh1 - Eh2);
                    float2 Rb = sdmix(Sb, Db, Pb, Pb);
                    cbuf[0] = make_float2(Ra.x + Rb.x, Ra.y + Rb.y);
                    cbuf[1] = make_float2(Ra.x - Rb.x, Ra.y - Rb.y);
                }
                {
                    float wu = c2pi * 2048.0f / 8191.0f;
                    float h1 = __expf(-wu * d1), h2 = __expf(-wu * d2);
                    float h1b = h1 * Eh1, h2b = h2 * Eh2;
                    float Hs1a = 0.5f * (h1 + E1 / h1);
                    float Hs2a = 0.5f * (h2 + E2 / h2);
                    float Hs1b = 0.5f * (h1b + E1 / h1b);
                    float Hs2b = 0.5f * (h2b + E2 / h2b);
                    float Sa = 0.5f * (Hs1a + Hs2a), Da = 0.5f * (Hs1a - Hs2a);
                    float Sb = 0.5f * (Hs1b + Hs2b), Db = 0.5f * (Hs1b - Hs2b);
                    float2 g0 = cbuf[2], g1 = cbuf[3];
                    float2 Pa = make_float2(g0.x + g1.x, g0.y + g1.y);
                    float2 Pb = make_float2(g0.x - g1.x, g0.y - g1.y);
                    float2 Ra = sdmix(Sa, Da, Pa, Pb);
                    float2 Rb = sdmix(Sb, Db, Pb, Pa);
                    cbuf[2] = make_float2(Ra.x + Rb.x, Ra.y + Rb.y);
                    cbuf[3] = make_float2(Ra.x - Rb.x, Ra.y - Rb.y);
                }
            } else {
                const int u2 = 4096 - u;
                const int c  = (int)(__brev((unsigned)u)  >> 20);
                const int c2 = (int)(__brev((unsigned)u2) >> 20);
                float2 g0 = cbuf[2 * c],  g1 = cbuf[2 * c + 1];
                float2 q0 = cbuf[2 * c2], q1 = cbuf[2 * c2 + 1];
                float2 Pa  = make_float2(g0.x + g1.x, g0.y + g1.y);
                float2 Pb  = make_float2(g0.x - g1.x, g0.y - g1.y);
                float2 Pa2 = make_float2(q0.x + q1.x, q0.y + q1.y);
                float2 Pb2 = make_float2(q0.x - q1.x, q0.y - q1.y);
                float wu = c2pi * (float)u / 8191.0f;
                float h1 = __expf(-wu * d1), h2 = __expf(-wu * d2);
                float h1b = h1 * Eh1, h2b = h2 * Eh2;
                float Hs1a = 0.5f * (h1 + E1 / h1);
                float Hs2a = 0.5f * (h2 + E2 / h2);
                float Hs1b = 0.5f * (h1b + E1 / h1b);
                float Hs2b = 0.5f * (h2b + E2 / h2b);
                float Sa = 0.5f * (Hs1a + Hs2a), Da = 0.5f * (Hs1a - Hs2a);
                float Sb = 0.5f * (Hs1b + Hs2b), Db = 0.5f * (Hs1b - Hs2b);
                float2 Ra  = sdmix(Sa, Da, Pa,  Pb2);
                float2 Rb2 = sdmix(Sa, Da, Pb2, Pa);
                float2 Rb  = sdmix(Sb, Db, Pb,  Pa2);
                float2 Ra2 = sdmix(Sb, Db, Pa2, Pb);
                cbuf[2 * c]      = make_float2(Ra.x + Rb.x,   Ra.y + Rb.y);
                cbuf[2 * c + 1]  = make_float2(Ra.x - Rb.x,   Ra.y - Rb.y);
                cbuf[2 * c2]     = make_float2(Ra2.x + Rb2.x, Ra2.y + Rb2.y);
                cbuf[2 * c2 + 1] = make_float2(Ra2.x - Rb2.x, Ra2.y - Rb2.y);
            }
        }
        __syncthreads();
    }

    #pragma unroll
    for (int h = 2; h <= 512; h <<= 2) {
        #pragma unroll
        for (int u = 0; u < 4; ++u) {
            const int q  = t + u * 512;
            const int jj = q & (h - 1);
            const int i0 = ((q - jj) << 2) + jj;
            float2 c0 = cbuf[i0];
            float2 c1 = cbuf[i0 + h];
            float2 c2 = cbuf[i0 + 2 * h];
            float2 c3 = cbuf[i0 + 3 * h];
            float sa, ca;
            __sincosf(cpi * (float)jj / (float)(2 * h), &sa, &ca);
            const float2 tw1  = make_float2(2.0f * ca * ca - 1.0f, 2.0f * sa * ca);
            const float2 tw2a = make_float2(ca, sa);
            const float2 tw2b = make_float2(-sa, ca);
            float2 t0 = cmul(c1, tw1);
            float2 a0 = make_float2(c0.x + t0.x, c0.y + t0.y);
            float2 a1 = make_float2(c0.x - t0.x, c0.y - t0.y);
            float2 t1 = cmul(c3, tw1);
            float2 b0 = make_float2(c2.x + t1.x, c2.y + t1.y);
            float2 b1 = make_float2(c2.x - t1.x, c2.y - t1.y);
            float2 t2 = cmul(b0, tw2a);
            cbuf[i0]         = make_float2(a0.x + t2.x, a0.y + t2.y);
            cbuf[i0 + 2 * h] = make_float2(a0.x - t2.x, a0.y - t2.y);
            float2 t3 = cmul(b1, tw2b);
            cbuf[i0 + h]     = make_float2(a1.x + t3.x, a1.y + t3.y);
            cbuf[i0 + 3 * h] = make_float2(a1.x - t3.x, a1.y - t3.y);
        }
        __syncthreads();
    }

    {
        const int h = 2048;
        const float inv = 1.0f / (float)N_;
        #pragma unroll
        for (int u = 0; u < 4; ++u) {
            const int jj = t + u * 512;
            const int i0 = jj;
            float2 c0 = cbuf[i0];
            float2 c1 = cbuf[i0 + h];
            float2 c2 = cbuf[i0 + 2 * h];
            float2 c3 = cbuf[i0 + 3 * h];
            float sa, ca;
            __sincosf(cpi * (float)jj / (float)(2 * h), &sa, &ca);
            const float2 tw1  = make_float2(2.0f * ca * ca - 1.0f, 2.0f * sa * ca);
            const float2 tw2a = make_float2(ca, sa);
            const float2 tw2b = make_float2(-sa, ca);
            float2 t0 = cmul(c1, tw1);
            float2 a0 = make_float2(c0.x + t0.x, c0.y + t0.y);
            float2 a1 = make_float2(c0.x - t0.x, c0.y - t0.y);
            float2 t1 = cmul(c3, tw1);
            float2 b0 = make_float2(c2.x + t1.x, c2.y + t1.y);
            float2 b1 = make_float2(c2.x - t1.x, c2.y - t1.y);
            float2 t2 = cmul(b0, tw2a);
            float2 o0 = make_float2(a0.x + t2.x, a0.y + t2.y);
            float2 o2 = make_float2(a0.x - t2.x, a0.y - t2.y);
            float2 t3 = cmul(b1, tw2b);
            float2 o1 = make_float2(a1.x + t3.x, a1.y + t3.y);
            float2 o3 = make_float2(a1.x - t3.x, a1.y - t3.y);
            row1[i0]         = o0.x * inv;  row2[i0]         = o0.y * inv;
            row1[i0 + h]     = o1.x * inv;  row2[i0 + h]     = o1.y * inv;
            row1[i0 + 2*h]   = o2.x * inv;  row2[i0 + 2*h]   = o2.y * inv;
            row1[i0 + 3*h]   = o3.x * inv;  row2[i0 + 3*h]   = o3.y * inv;
        }
    }
}

// ---------------------------------------------------------------------------
// K5: t[b,n,r] = sum_k y[b,k,n] * U[k,r];  out = x + t @ G^T + bu
// ---------------------------------------------------------------------------
__global__ void out_kernel(const float* __restrict__ x,
                           const float* __restrict__ y_t,
                           const float* __restrict__ U,
                           const float* __restrict__ G,
                           const float* __restrict__ bu,
                           float*       __restrict__ out) {
    __shared__ float ttile[64][R_];
    const int blk = blockIdx.x;          // 2048
    const int b   = blk >> 7;
    const int n0  = (blk & 127) << 6;
    const int t   = threadIdx.x;

    {
        const int nl = t >> 2, r = t & 3;
        const float* yb = y_t + (size_t)b * BN_ * N_ + n0 + nl;
        float s = 0.0f;
        #pragma unroll
        for (int kk = 0; kk < BN_; ++kk) s += yb[(size_t)kk * N_] * U[kk * R_ + r];
        ttile[nl][r] = s;
    }
    __syncthreads();

    float4 g = *(const float4*)(G + t * 4);
    float bv = bu[t];
    const float* xb = x   + ((size_t)b * N_ + n0) * D_;
    float*       ob = out + ((size_t)b * N_ + n0) * D_;
    for (int nl = 0; nl < 64; ++nl) {
        float t0 = ttile[nl][0], t1 = ttile[nl][1];
        float t2 = ttile[nl][2], t3 = ttile[nl][3];
        ob[nl * D_ + t] = xb[nl * D_ + t]
                        + t0 * g.x + t1 * g.y + t2 * g.z + t3 * g.w + bv;
    }
}

// ---------------------------------------------------------------------------
extern "C" void kernel_launch(void* const* d_in, const int* in_sizes, int n_in,
                              void* d_out, int out_size, void* d_ws, size_t ws_size,
                              hipStream_t stream) {
    const float* x       = (const float*)d_in[0];
    const float* coords  = (const float*)d_in[1];
    const float* Wd      = (const float*)d_in[2];
    const float* bd      = (const float*)d_in[3];
    const float* U       = (const float*)d_in[4];
    const float* V       = (const float*)d_in[5];
    const float* logit_d = (const float*)d_in[6];
    const float* Wu      = (const float*)d_in[7];
    const float* bu      = (const float*)d_in[8];
    float* out = (float*)d_out;

    char* ws = (char*)d_ws;
    int*            order  = (int*)ws;                             // 512 KB
    float*          G      = (float*)(ws + 1536 * 1024);           // 4 KB
    unsigned short* wdpack = (unsigned short*)(ws + 1792 * 1024);  // 16 KB
    float*          zpk    = (float*)(ws + 2048 * 1024);           // 16 MB
    float*          zkp    = (float*)(ws + (2048 + 16384) * 1024); // 16 MB

    prep_kernel  <<<dim3(1),          dim3(256),  0, stream>>>(Wu, V, Wd, G, wdpack);
    fat_kernel   <<<dim3(B_ + 512),   dim3(1024), 64 * 1024, stream>>>(x, coords, wdpack, order, zpk);
    zgather_kernel<<<dim3(B_ * 128),  dim3(512),  0, stream>>>(zpk, coords, Wd, bd, order, zkp);
    fft_filter_kernel<<<dim3(B_ * 16), dim3(512), 64 * 1024, stream>>>(zkp, logit_d);
    out_kernel   <<<dim3(B_ * 128),   dim3(256),  0, stream>>>(x, zkp, U, G, bu, out);
}

// Round 15
// 147.036 us; speedup vs baseline: 1.1037x; 1.0111x over previous
//
#include <hip/hip_runtime.h>
#include <math.h>

#define B_    16
#define N_    8192
#define D_    256
#define BN_   32
#define R_    4
#define LOGN  13

typedef float  f32x4  __attribute__((ext_vector_type(4)));
typedef short  s16x8  __attribute__((ext_vector_type(8)));
typedef unsigned long long ull;
typedef ull    ull2   __attribute__((ext_vector_type(2)));

// FFT LDS pad: i -> i + i/16. Kills power-of-2-stride and bit-reversed
// bank aliasing for 8B elements (textbook). Max 8191 -> 8702 (68 KB).
__device__ __forceinline__ int PAD(int i) { return i + (i >> 4); }

// ---------------------------------------------------------------------------
// Morton helpers (exact replica of reference bit-interleave)
// ---------------------------------------------------------------------------
__device__ __forceinline__ ull interleave3(ull v) {
    v = v & 2097151ULL;
    v = v | (v << 32);
    v = v & 8725724278095871ULL;
    v = v | ((v << 16) & 8725728556220671ULL);
    v = v | ((v << 8)  & 282506020581391ULL);
    v = v | ((v << 4)  & 294878547030211ULL);
    v = v | ((v << 2)  & 321685687669321ULL);
    return v;
}

__device__ __forceinline__ long long quant10(float c) {
    long long v = (long long)(c * 1023.0f);
    v = v < 0 ? 0 : (v > 1023 ? 1023 : v);
    return v;
}

__device__ __forceinline__ unsigned short f2bf(float f) {
    unsigned u = __float_as_uint(f);
    u = (u + 0x7FFF + ((u >> 16) & 1)) >> 16;   // RNE
    return (unsigned short)u;
}

__device__ __forceinline__ unsigned cvtpk_bf16(float lo, float hi) {
    unsigned r;
    asm("v_cvt_pk_bf16_f32 %0, %1, %2" : "=v"(r) : "v"(lo), "v"(hi));
    return r;
}

__device__ __forceinline__ void cswap(ull& a, ull& b, bool up) {
    ull lo = a < b ? a : b;
    ull hi = a < b ? b : a;
    a = up ? lo : hi;
    b = up ? hi : lo;
}

// ---------------------------------------------------------------------------
// P0: prep — G = Wu @ V  [256,4]  and  Wd packed to bf16 [32][256] row-major.
// ---------------------------------------------------------------------------
__global__ void prep_kernel(const float* __restrict__ Wu, const float* __restrict__ V,
                            const float* __restrict__ Wd,
                            float* __restrict__ G, unsigned short* __restrict__ wdpack) {
    const int t = threadIdx.x;   // 256
    for (int r = 0; r < R_; ++r) {
        float s = 0.0f;
        for (int kk = 0; kk < BN_; ++kk) s += Wu[t * BN_ + kk] * V[kk * R_ + r];
        G[t * R_ + r] = s;
    }
    for (int i = t; i < BN_ * 256; i += 256) {
        const int row = i >> 8, col = i & 255;
        wdpack[i] = f2bf(Wd[row * 257 + col]);
    }
}

// ---------------------------------------------------------------------------
// FAT kernel (1024 threads): r14's proven version (conflict-free sort +
// direct-reg streaming MFMA), unchanged.
// ---------------------------------------------------------------------------
__global__ __launch_bounds__(1024)
void fat_kernel(const float* __restrict__ x,
                const float* __restrict__ coords,
                const unsigned short* __restrict__ wdpack,
                int* __restrict__ order,
                float* __restrict__ z_pk) {
    extern __shared__ ull skey[];          // 8192 * 8B = 64 KB
    const int bid = blockIdx.x;
    const int t   = threadIdx.x;

    if (bid < B_) {
        const int b = bid;
        // ---- init pass: morton keys + in-register sort-8 (sizes 2,4,8) ----
        {
            const int i0 = t * 8;
            ull K[8];
            #pragma unroll
            for (int j = 0; j < 8; ++j) {
                const float* c = coords + ((size_t)b * N_ + i0 + j) * 3;
                ull mx = interleave3((ull)quant10(c[0]));
                ull my = interleave3((ull)quant10(c[1]));
                ull mz = interleave3((ull)quant10(c[2]));
                ull m = mx | (my << 1) | (mz << 2);
                K[j] = (m << LOGN) | (ull)(i0 + j);
            }
            cswap(K[0], K[1], true);  cswap(K[2], K[3], false);
            cswap(K[4], K[5], true);  cswap(K[6], K[7], false);
            cswap(K[0], K[2], true);  cswap(K[1], K[3], true);
            cswap(K[4], K[6], false); cswap(K[5], K[7], false);
            cswap(K[0], K[1], true);  cswap(K[2], K[3], true);
            cswap(K[4], K[5], false); cswap(K[6], K[7], false);
            const bool U = ((t & 1) == 0);
            cswap(K[0], K[4], U); cswap(K[1], K[5], U);
            cswap(K[2], K[6], U); cswap(K[3], K[7], U);
            cswap(K[0], K[2], U); cswap(K[1], K[3], U);
            cswap(K[4], K[6], U); cswap(K[5], K[7], U);
            cswap(K[0], K[1], U); cswap(K[2], K[3], U);
            cswap(K[4], K[5], U); cswap(K[6], K[7], U);
            ull2* p2 = (ull2*)&skey[i0];
            #pragma unroll
            for (int j = 0; j < 4; ++j) { ull2 w; w.x = K[2*j]; w.y = K[2*j+1]; p2[j] = w; }
        }
        __syncthreads();

        for (int k = 4; k <= LOGN; ++k) {
            const int size = 1 << k;
            int s = size >> 1;

            while (s >= 32) {
                const int q  = s >> 2;
                const int jj = t & (q - 1);
                const int i0 = ((t - jj) << 3) + jj;
                ull K[8];
                #pragma unroll
                for (int j = 0; j < 8; ++j) K[j] = skey[i0 + j * q];
                const bool up = ((i0 & size) == 0);
                cswap(K[0], K[4], up); cswap(K[1], K[5], up);
                cswap(K[2], K[6], up); cswap(K[3], K[7], up);
                cswap(K[0], K[2], up); cswap(K[1], K[3], up);
                cswap(K[4], K[6], up); cswap(K[5], K[7], up);
                cswap(K[0], K[1], up); cswap(K[2], K[3], up);
                cswap(K[4], K[5], up); cswap(K[6], K[7], up);
                #pragma unroll
                for (int j = 0; j < 8; ++j) skey[i0 + j * q] = K[j];
                __syncthreads();
                s >>= 3;
            }

            if (s == 16) {
                #pragma unroll
                for (int u = 0; u < 2; ++u) {
                    const int p  = t + u * 1024;
                    const int jj = p & 7;
                    const int i0 = ((p - jj) << 2) + jj;
                    ull K0 = skey[i0], K1 = skey[i0 + 8];
                    ull K2 = skey[i0 + 16], K3 = skey[i0 + 24];
                    const bool up = ((i0 & size) == 0);
                    cswap(K0, K2, up); cswap(K1, K3, up);
                    cswap(K0, K1, up); cswap(K2, K3, up);
                    skey[i0] = K0; skey[i0 + 8] = K1;
                    skey[i0 + 16] = K2; skey[i0 + 24] = K3;
                }
                __syncthreads();
            } else if (s == 8) {
                #pragma unroll
                for (int u = 0; u < 4; ++u) {
                    const int p  = t + u * 1024;
                    const int jj = p & 7;
                    const int i  = ((p - jj) << 1) + jj;
                    ull a = skey[i], c = skey[i + 8];
                    cswap(a, c, ((i & size) == 0));
                    skey[i] = a; skey[i + 8] = c;
                }
                __syncthreads();
            }

            {
                const int i0 = t * 8;
                ull K[8];
                ull2* p2 = (ull2*)&skey[i0];
                #pragma unroll
                for (int j = 0; j < 4; ++j) { ull2 w = p2[j]; K[2*j] = w.x; K[2*j+1] = w.y; }
                const bool up = ((i0 & size) == 0);
                cswap(K[0], K[4], up); cswap(K[1], K[5], up);
                cswap(K[2], K[6], up); cswap(K[3], K[7], up);
                cswap(K[0], K[2], up); cswap(K[1], K[3], up);
                cswap(K[4], K[6], up); cswap(K[5], K[7], up);
                cswap(K[0], K[1], up); cswap(K[2], K[3], up);
                cswap(K[4], K[5], up); cswap(K[6], K[7], up);
                if (k == LOGN) {
                    #pragma unroll
                    for (int j = 0; j < 8; ++j)
                        order[b * N_ + i0 + j] = (int)(K[j] & (ull)(N_ - 1));
                } else {
                    #pragma unroll
                    for (int j = 0; j < 4; ++j) { ull2 w; w.x = K[2*j]; w.y = K[2*j+1]; p2[j] = w; }
                    __syncthreads();
                }
            }
        }
    } else {
        // ===== zgemm_nat: 256 rows/block, direct global->reg fragments =====
        const int zb  = bid - B_;               // 0..511
        const int b   = zb >> 5;
        const int m0  = (zb & 31) << 8;
        const int w   = t >> 6;
        const int l   = t & 63;
        const int lg  = l >> 4;
        const int lm  = l & 15;

        s16x8 wf0[8], wf1[8];
        #pragma unroll
        for (int kc = 0; kc < 8; ++kc) {
            wf0[kc] = *(const s16x8*)(wdpack + lm * 256        + kc * 32 + lg * 8);
            wf1[kc] = *(const s16x8*)(wdpack + (lm + 16) * 256 + kc * 32 + lg * 8);
        }

        const int xr = w * 16 + lm;
        const float* xrow = x + ((size_t)(b * N_ + m0 + xr)) * D_;

        f32x4 acc0 = {0.f, 0.f, 0.f, 0.f};
        f32x4 acc1 = {0.f, 0.f, 0.f, 0.f};
        #pragma unroll
        for (int kc = 0; kc < 8; ++kc) {
            const float4 va = *(const float4*)(xrow + kc * 32 + lg * 8);
            const float4 vb = *(const float4*)(xrow + kc * 32 + lg * 8 + 4);
            union { s16x8 v; unsigned u[4]; } bu_;
            bu_.u[0] = cvtpk_bf16(va.x, va.y);
            bu_.u[1] = cvtpk_bf16(va.z, va.w);
            bu_.u[2] = cvtpk_bf16(vb.x, vb.y);
            bu_.u[3] = cvtpk_bf16(vb.z, vb.w);
            acc0 = __builtin_amdgcn_mfma_f32_16x16x32_bf16(wf0[kc], bu_.v, acc0, 0, 0, 0);
            acc1 = __builtin_amdgcn_mfma_f32_16x16x32_bf16(wf1[kc], bu_.v, acc1, 0, 0, 0);
        }

        const int m = m0 + xr;
        float* zb_ = z_pk + ((size_t)(b * N_ + m)) * BN_;
        float4 v0, v1;
        v0.x = acc0[0]; v0.y = acc0[1]; v0.z = acc0[2]; v0.w = acc0[3];
        v1.x = acc1[0]; v1.y = acc1[1]; v1.z = acc1[2]; v1.w = acc1[3];
        *(float4*)(zb_ + lg * 4)      = v0;
        *(float4*)(zb_ + 16 + lg * 4) = v1;
    }
}

// ---------------------------------------------------------------------------
// ZG: permutation + radius + bias + relu + transpose to k-major (r14 ver).
// ---------------------------------------------------------------------------
__global__ __launch_bounds__(512)
void zgather_kernel(const float* __restrict__ z_pk,
                    const float* __restrict__ coords,
                    const float* __restrict__ Wd,
                    const float* __restrict__ bd,
                    const int*   __restrict__ order,
                    float*       __restrict__ z_kp) {
    __shared__ float ltile[64][33];
    __shared__ float sWdLast[BN_];
    __shared__ float sbd[BN_];
    const int blk = blockIdx.x;           // 2048
    const int b   = blk >> 7;
    const int p0  = (blk & 127) << 6;
    const int t   = threadIdx.x;

    if (t < BN_) { sWdLast[t] = Wd[(size_t)t * 257 + 256]; sbd[t] = bd[t]; }
    __syncthreads();

    {
        const int sl = t >> 3;
        const int kc = t & 7;
        const int p  = p0 + sl;
        const int od = order[b * N_ + p];
        float4 v = *(const float4*)(z_pk + ((size_t)(b * N_ + od)) * BN_ + kc * 4);
        const float* c = coords + ((size_t)(b * N_ + p)) * 3;
        const float rr = sqrtf(c[0] * c[0] + c[1] * c[1] + c[2] * c[2]);
        v.x = fmaxf(v.x + rr * sWdLast[kc * 4 + 0] + sbd[kc * 4 + 0], 0.0f);
        v.y = fmaxf(v.y + rr * sWdLast[kc * 4 + 1] + sbd[kc * 4 + 1], 0.0f);
        v.z = fmaxf(v.z + rr * sWdLast[kc * 4 + 2] + sbd[kc * 4 + 2], 0.0f);
        v.w = fmaxf(v.w + rr * sWdLast[kc * 4 + 3] + sbd[kc * 4 + 3], 0.0f);
        ltile[sl][kc * 4 + 0] = v.x;
        ltile[sl][kc * 4 + 1] = v.y;
        ltile[sl][kc * 4 + 2] = v.z;
        ltile[sl][kc * 4 + 3] = v.w;
    }
    __syncthreads();

    {
        const int k  = t >> 4;
        const int pc = t & 15;
        float4 o;
        o.x = ltile[pc * 4 + 0][k];
        o.y = ltile[pc * 4 + 1][k];
        o.z = ltile[pc * 4 + 2][k];
        o.w = ltile[pc * 4 + 3][k];
        *(float4*)(z_kp + (size_t)(b * BN_ + k) * N_ + p0 + pc * 4) = o;
    }
}

// ---------------------------------------------------------------------------
// K4: PAIR-PACKED spectral filter with PADDED LDS indexing (conflict fix).
// ---------------------------------------------------------------------------
__device__ __forceinline__ float2 cmul(float2 a, float2 b) {
    return make_float2(a.x * b.x - a.y * b.y, a.x * b.y + a.y * b.x);
}
__device__ __forceinline__ float2 sdmix(float S, float D, float2 P, float2 Q) {
    return make_float2(S * P.x + D * Q.x, S * P.y - D * Q.y);
}

__global__ __launch_bounds__(512)
void fft_filter_kernel(float* __restrict__ zy,
                       const float* __restrict__ logit_d) {
    extern __shared__ float2 cbuf[];   // 8704 * 8B = 68 KB (padded)

    const int bk = blockIdx.x;     // 256 = B_ * 16
    const int b  = bk >> 4;
    const int kp = bk & 15;
    const int t  = threadIdx.x;

    float* row1 = zy + (size_t)(b * BN_ + 2 * kp) * N_;
    float* row2 = row1 + N_;

    float d1 = fminf(fmaxf(logit_d[2 * kp],     -10.0f), 10.0f);
    float d2 = fminf(fmaxf(logit_d[2 * kp + 1], -10.0f), 10.0f);

    const float cpi  = 3.14159265358979323846f;
    const float c2pi = 6.28318530717958647692f;
    const float A    = c2pi * 8192.0f / 8191.0f;

    const float Eh1 = __expf(-0.5f * A * d1), E1 = Eh1 * Eh1;
    const float Eh2 = __expf(-0.5f * A * d2), E2 = Eh2 * Eh2;

    // ---- F1: fused forward (4096,2048), complex input from GLOBAL ----
    {
        const int h = 4096, hh = 2048;
        #pragma unroll
        for (int u = 0; u < 4; ++u) {
            const int i0 = t + u * 512;
            float2 c0 = make_float2(row1[i0],            row2[i0]);
            float2 c1 = make_float2(row1[i0 + hh],       row2[i0 + hh]);
            float2 c2 = make_float2(row1[i0 + h],        row2[i0 + h]);
            float2 c3 = make_float2(row1[i0 + h + hh],   row2[i0 + h + hh]);
            float sA, cA;
            __sincosf(-cpi * (float)i0 / (float)h, &sA, &cA);
            const float2 twA1 = make_float2(cA, sA);
            const float2 twA2 = make_float2(sA, -cA);
            const float2 twB  = make_float2(2.0f * cA * cA - 1.0f, 2.0f * sA * cA);
            float2 a0 = make_float2(c0.x + c2.x, c0.y + c2.y);
            float2 a1 = make_float2(c1.x + c3.x, c1.y + c3.y);
            float2 b0 = cmul(make_float2(c0.x - c2.x, c0.y - c2.y), twA1);
            float2 b1 = cmul(make_float2(c1.x - c3.x, c1.y - c3.y), twA2);
            cbuf[PAD(i0)]          = make_float2(a0.x + a1.x, a0.y + a1.y);
            cbuf[PAD(i0 + hh)]     = cmul(make_float2(a0.x - a1.x, a0.y - a1.y), twB);
            cbuf[PAD(i0 + h)]      = make_float2(b0.x + b1.x, b0.y + b1.y);
            cbuf[PAD(i0 + h + hh)] = cmul(make_float2(b0.x - b1.x, b0.y - b1.y), twB);
        }
        __syncthreads();
    }

    // ---- F2..F6: fused forward (h, h/2) for h = 1024,256,64,16,4 ----
    #pragma unroll
    for (int h = 1024; h >= 4; h >>= 2) {
        const int hh = h >> 1;
        #pragma unroll
        for (int u = 0; u < 4; ++u) {
            const int q   = t + u * 512;
            const int jj  = q & (hh - 1);
            const int i0  = ((q - jj) << 2) + jj;
            float2 c0 = cbuf[PAD(i0)];
            float2 c1 = cbuf[PAD(i0 + hh)];
            float2 c2 = cbuf[PAD(i0 + h)];
            float2 c3 = cbuf[PAD(i0 + h + hh)];
            float sA, cA;
            __sincosf(-cpi * (float)jj / (float)h, &sA, &cA);
            const float2 twA1 = make_float2(cA, sA);
            const float2 twA2 = make_float2(sA, -cA);
            const float2 twB  = make_float2(2.0f * cA * cA - 1.0f, 2.0f * sA * cA);
            float2 a0 = make_float2(c0.x + c2.x, c0.y + c2.y);
            float2 a1 = make_float2(c1.x + c3.x, c1.y + c3.y);
            float2 b0 = cmul(make_float2(c0.x - c2.x, c0.y - c2.y), twA1);
            float2 b1 = cmul(make_float2(c1.x - c3.x, c1.y - c3.y), twA2);
            cbuf[PAD(i0)]          = make_float2(a0.x + a1.x, a0.y + a1.y);
            cbuf[PAD(i0 + hh)]     = cmul(make_float2(a0.x - a1.x, a0.y - a1.y), twB);
            cbuf[PAD(i0 + h)]      = make_float2(b0.x + b1.x, b0.y + b1.y);
            cbuf[PAD(i0 + h + hh)] = cmul(make_float2(b0.x - b1.x, b0.y - b1.y), twB);
        }
        __syncthreads();
    }

    // ---- M: fwd h=1 + Hermitian unpack * Hsym + repack + inv h=1 ----
    {
        #pragma unroll
        for (int v = 0; v < 4; ++v) {
            const int u = t + v * 512;
            if (u == 0) {
                {   // PAD(0..3) == 0..3
                    float2 g0 = cbuf[0], g1 = cbuf[1];
                    float2 Pa = make_float2(g0.x + g1.x, g0.y + g1.y);
                    float2 Pb = make_float2(g0.x - g1.x, g0.y - g1.y);
                    float2 Ra = Pa;
                    float Sb = 0.5f * (Eh1 + Eh2), Db = 0.5f * (Eh1 - Eh2);
                    float2 Rb = sdmix(Sb, Db, Pb, Pb);
                    cbuf[0] = make_float2(Ra.x + Rb.x, Ra.y + Rb.y);
                    cbuf[1] = make_float2(Ra.x - Rb.x, Ra.y - Rb.y);
                }
                {
                    float wu = c2pi * 2048.0f / 8191.0f;
                    float h1 = __expf(-wu * d1), h2 = __expf(-wu * d2);
                    float h1b = h1 * Eh1, h2b = h2 * Eh2;
                    float Hs1a = 0.5f * (h1 + E1 / h1);
                    float Hs2a = 0.5f * (h2 + E2 / h2);
                    float Hs1b = 0.5f * (h1b + E1 / h1b);
                    float Hs2b = 0.5f * (h2b + E2 / h2b);
                    float Sa = 0.5f * (Hs1a + Hs2a), Da = 0.5f * (Hs1a - Hs2a);
                    float Sb = 0.5f * (Hs1b + Hs2b), Db = 0.5f * (Hs1b - Hs2b);
                    float2 g0 = cbuf[2], g1 = cbuf[3];
                    float2 Pa = make_float2(g0.x + g1.x, g0.y + g1.y);
                    float2 Pb = make_float2(g0.x - g1.x, g0.y - g1.y);
                    float2 Ra = sdmix(Sa, Da, Pa, Pb);
                    float2 Rb = sdmix(Sb, Db, Pb, Pa);
                    cbuf[2] = make_float2(Ra.x + Rb.x, Ra.y + Rb.y);
                    cbuf[3] = make_float2(Ra.x - Rb.x, Ra.y - Rb.y);
                }
            } else {
                const int u2 = 4096 - u;
                const int c  = (int)(__brev((unsigned)u)  >> 20);
                const int c2 = (int)(__brev((unsigned)u2) >> 20);
                const int s0 = PAD(2 * c),  s1 = PAD(2 * c + 1);
                const int s2 = PAD(2 * c2), s3 = PAD(2 * c2 + 1);
                float2 g0 = cbuf[s0], g1 = cbuf[s1];
                float2 q0 = cbuf[s2], q1 = cbuf[s3];
                float2 Pa  = make_float2(g0.x + g1.x, g0.y + g1.y);
                float2 Pb  = make_float2(g0.x - g1.x, g0.y - g1.y);
                float2 Pa2 = make_float2(q0.x + q1.x, q0.y + q1.y);
                float2 Pb2 = make_float2(q0.x - q1.x, q0.y - q1.y);
                float wu = c2pi * (float)u / 8191.0f;
                float h1 = __expf(-wu * d1), h2 = __expf(-wu * d2);
                float h1b = h1 * Eh1, h2b = h2 * Eh2;
                float Hs1a = 0.5f * (h1 + E1 / h1);
                float Hs2a = 0.5f * (h2 + E2 / h2);
                float Hs1b = 0.5f * (h1b + E1 / h1b);
                float Hs2b = 0.5f * (h2b + E2 / h2b);
                float Sa = 0.5f * (Hs1a + Hs2a), Da = 0.5f * (Hs1a - Hs2a);
                float Sb = 0.5f * (Hs1b + Hs2b), Db = 0.5f * (Hs1b - Hs2b);
                float2 Ra  = sdmix(Sa, Da, Pa,  Pb2);
                float2 Rb2 = sdmix(Sa, Da, Pb2, Pa);
                float2 Rb  = sdmix(Sb, Db, Pb,  Pa2);
                float2 Ra2 = sdmix(Sb, Db, Pa2, Pb);
                cbuf[s0] = make_float2(Ra.x + Rb.x,   Ra.y + Rb.y);
                cbuf[s1] = make_float2(Ra.x - Rb.x,   Ra.y - Rb.y);
                cbuf[s2] = make_float2(Ra2.x + Rb2.x, Ra2.y + Rb2.y);
                cbuf[s3] = make_float2(Ra2.x - Rb2.x, Ra2.y - Rb2.y);
            }
        }
        __syncthreads();
    }

    // ---- I1..I5: fused inverse (h, 2h) for h = 2,8,32,128,512 ----
    #pragma unroll
    for (int h = 2; h <= 512; h <<= 2) {
        #pragma unroll
        for (int u = 0; u < 4; ++u) {
            const int q  = t + u * 512;
            const int jj = q & (h - 1);
            const int i0 = ((q - jj) << 2) + jj;
            float2 c0 = cbuf[PAD(i0)];
            float2 c1 = cbuf[PAD(i0 + h)];
            float2 c2 = cbuf[PAD(i0 + 2 * h)];
            float2 c3 = cbuf[PAD(i0 + 3 * h)];
            float sa, ca;
            __sincosf(cpi * (float)jj / (float)(2 * h), &sa, &ca);
            const float2 tw1  = make_float2(2.0f * ca * ca - 1.0f, 2.0f * sa * ca);
            const float2 tw2a = make_float2(ca, sa);
            const float2 tw2b = make_float2(-sa, ca);
            float2 t0 = cmul(c1, tw1);
            float2 a0 = make_float2(c0.x + t0.x, c0.y + t0.y);
            float2 a1 = make_float2(c0.x - t0.x, c0.y - t0.y);
            float2 t1 = cmul(c3, tw1);
            float2 b0 = make_float2(c2.x + t1.x, c2.y + t1.y);
            float2 b1 = make_float2(c2.x - t1.x, c2.y - t1.y);
            float2 t2 = cmul(b0, tw2a);
            cbuf[PAD(i0)]         = make_float2(a0.x + t2.x, a0.y + t2.y);
            cbuf[PAD(i0 + 2 * h)] = make_float2(a0.x - t2.x, a0.y - t2.y);
            float2 t3 = cmul(b1, tw2b);
            cbuf[PAD(i0 + h)]     = make_float2(a1.x + t3.x, a1.y + t3.y);
            cbuf[PAD(i0 + 3 * h)] = make_float2(a1.x - t3.x, a1.y - t3.y);
        }
        __syncthreads();
    }

    // ---- I6: fused inverse (2048, 4096), scaled split write to GLOBAL ----
    {
        const int h = 2048;
        const float inv = 1.0f / (float)N_;
        #pragma unroll
        for (int u = 0; u < 4; ++u) {
            const int jj = t + u * 512;
            const int i0 = jj;
            float2 c0 = cbuf[PAD(i0)];
            float2 c1 = cbuf[PAD(i0 + h)];
            float2 c2 = cbuf[PAD(i0 + 2 * h)];
            float2 c3 = cbuf[PAD(i0 + 3 * h)];
            float sa, ca;
            __sincosf(cpi * (float)jj / (float)(2 * h), &sa, &ca);
            const float2 tw1  = make_float2(2.0f * ca * ca - 1.0f, 2.0f * sa * ca);
            const float2 tw2a = make_float2(ca, sa);
            const float2 tw2b = make_float2(-sa, ca);
            float2 t0 = cmul(c1, tw1);
            float2 a0 = make_float2(c0.x + t0.x, c0.y + t0.y);
            float2 a1 = make_float2(c0.x - t0.x, c0.y - t0.y);
            float2 t1 = cmul(c3, tw1);
            float2 b0 = make_float2(c2.x + t1.x, c2.y + t1.y);
            float2 b1 = make_float2(c2.x - t1.x, c2.y - t1.y);
            float2 t2 = cmul(b0, tw2a);
            float2 o0 = make_float2(a0.x + t2.x, a0.y + t2.y);
            float2 o2 = make_float2(a0.x - t2.x, a0.y - t2.y);
            float2 t3 = cmul(b1, tw2b);
            float2 o1 = make_float2(a1.x + t3.x, a1.y + t3.y);
            float2 o3 = make_float2(a1.x - t3.x, a1.y - t3.y);
            row1[i0]         = o0.x * inv;  row2[i0]         = o0.y * inv;
            row1[i0 + h]     = o1.x * inv;  row2[i0 + h]     = o1.y * inv;
            row1[i0 + 2*h]   = o2.x * inv;  row2[i0 + 2*h]   = o2.y * inv;
            row1[i0 + 3*h]   = o3.x * inv;  row2[i0 + 3*h]   = o3.y * inv;
        }
    }
}

// ---------------------------------------------------------------------------
// K5: t[b,n,r] = sum_k y[b,k,n]·U[k,r];  out = x + t @ G^T + bu.
// Phase A: lanes own consecutive n (256B coalesced loads of y rows).
// Phase B: float4 loads/stores (1KB per wave instruction).
// ---------------------------------------------------------------------------
__global__ __launch_bounds__(256)
void out_kernel(const float* __restrict__ x,
                const float* __restrict__ y_t,
                const float* __restrict__ U,
                const float* __restrict__ G,
                const float* __restrict__ bu,
                float*       __restrict__ out) {
    __shared__ float ttile[64][R_ + 1];
    const int blk = blockIdx.x;          // 2048
    const int b   = blk >> 7;
    const int n0  = (blk & 127) << 6;
    const int t   = threadIdx.x;

    // phase A: r = t>>6 (wave-uniform), nl = t&63 (lane -> consecutive n)
    {
        const int r = t >> 6, nl = t & 63;
        const float* yb = y_t + (size_t)b * BN_ * N_ + n0 + nl;
        float s = 0.0f;
        #pragma unroll
        for (int kk = 0; kk < BN_; ++kk) s += yb[(size_t)kk * N_] * U[kk * R_ + r];
        ttile[nl][r] = s;
    }
    __syncthreads();

    // phase B: d4 = t&63 (float4 along D), rg = t>>6 (4 rows in flight)
    const int d4 = t & 63, rg = t >> 6;
    const float4 g0 = *(const float4*)(G + (d4 * 4 + 0) * 4);
    const float4 g1 = *(const float4*)(G + (d4 * 4 + 1) * 4);
    const float4 g2 = *(const float4*)(G + (d4 * 4 + 2) * 4);
    const float4 g3 = *(const float4*)(G + (d4 * 4 + 3) * 4);
    const float4 bv = *(const float4*)(bu + d4 * 4);
    const float4* xb = (const float4*)(x   + ((size_t)(b * N_ + n0)) * D_);
    float4*       ob = (float4*)      (out + ((size_t)(b * N_ + n0)) * D_);
    #pragma unroll 4
    for (int nl = rg; nl < 64; nl += 4) {
        const float t0 = ttile[nl][0], t1 = ttile[nl][1];
        const float t2 = ttile[nl][2], t3 = ttile[nl][3];
        const float4 xv = xb[nl * 64 + d4];
        float4 o;
        o.x = xv.x + t0 * g0.x + t1 * g0.y + t2 * g0.z + t3 * g0.w + bv.x;
        o.y = xv.y + t0 * g1.x + t1 * g1.y + t2 * g1.z + t3 * g1.w + bv.y;
        o.z = xv.z + t0 * g2.x + t1 * g2.y + t2 * g2.z + t3 * g2.w + bv.z;
        o.w = xv.w + t0 * g3.x + t1 * g3.y + t2 * g3.z + t3 * g3.w + bv.w;
        ob[nl * 64 + d4] = o;
    }
}

// ---------------------------------------------------------------------------
extern "C" void kernel_launch(void* const* d_in, const int* in_sizes, int n_in,
                              void* d_out, int out_size, void* d_ws, size_t ws_size,
                              hipStream_t stream) {
    const float* x       = (const float*)d_in[0];
    const float* coords  = (const float*)d_in[1];
    const float* Wd      = (const float*)d_in[2];
    const float* bd      = (const float*)d_in[3];
    const float* U       = (const float*)d_in[4];
    const float* V       = (const float*)d_in[5];
    const float* logit_d = (const float*)d_in[6];
    const float* Wu      = (const float*)d_in[7];
    const float* bu      = (const float*)d_in[8];
    float* out = (float*)d_out;

    char* ws = (char*)d_ws;
    int*            order  = (int*)ws;                             // 512 KB
    float*          G      = (float*)(ws + 1536 * 1024);           // 4 KB
    unsigned short* wdpack = (unsigned short*)(ws + 1792 * 1024);  // 16 KB
    float*          zpk    = (float*)(ws + 2048 * 1024);           // 16 MB
    float*          zkp    = (float*)(ws + (2048 + 16384) * 1024); // 16 MB

    prep_kernel  <<<dim3(1),          dim3(256),  0, stream>>>(Wu, V, Wd, G, wdpack);
    fat_kernel   <<<dim3(B_ + 512),   dim3(1024), 64 * 1024, stream>>>(x, coords, wdpack, order, zpk);
    zgather_kernel<<<dim3(B_ * 128),  dim3(512),  0, stream>>>(zpk, coords, Wd, bd, order, zkp);
    fft_filter_kernel<<<dim3(B_ * 16), dim3(512), 8704 * 8, stream>>>(zkp, logit_d);
    out_kernel   <<<dim3(B_ * 128),   dim3(256),  0, stream>>>(x, zkp, U, G, bu, out);
}

// Round 16
// 135.029 us; speedup vs baseline: 1.2018x; 1.0889x over previous
//
#include <hip/hip_runtime.h>
#include <math.h>

#define B_    16
#define N_    8192
#define D_    256
#define BN_   32
#define R_    4
#define LOGN  13

typedef float  f32x4  __attribute__((ext_vector_type(4)));
typedef short  s16x8  __attribute__((ext_vector_type(8)));
typedef unsigned long long ull;
typedef ull    ull2   __attribute__((ext_vector_type(2)));

// FFT LDS pad: i -> i + i/16 (8B elems). 8191 -> 8702 (68 KB).
__device__ __forceinline__ int PAD(int i) { return i + (i >> 4); }

// ---------------------------------------------------------------------------
// Morton helpers (exact replica of reference bit-interleave)
// ---------------------------------------------------------------------------
__device__ __forceinline__ ull interleave3(ull v) {
    v = v & 2097151ULL;
    v = v | (v << 32);
    v = v & 8725724278095871ULL;
    v = v | ((v << 16) & 8725728556220671ULL);
    v = v | ((v << 8)  & 282506020581391ULL);
    v = v | ((v << 4)  & 294878547030211ULL);
    v = v | ((v << 2)  & 321685687669321ULL);
    return v;
}

__device__ __forceinline__ long long quant10(float c) {
    long long v = (long long)(c * 1023.0f);
    v = v < 0 ? 0 : (v > 1023 ? 1023 : v);
    return v;
}

__device__ __forceinline__ unsigned short f2bf(float f) {
    unsigned u = __float_as_uint(f);
    u = (u + 0x7FFF + ((u >> 16) & 1)) >> 16;   // RNE
    return (unsigned short)u;
}

__device__ __forceinline__ unsigned cvtpk_bf16(float lo, float hi) {
    unsigned r;
    asm("v_cvt_pk_bf16_f32 %0, %1, %2" : "=v"(r) : "v"(lo), "v"(hi));
    return r;
}

__device__ __forceinline__ void cswap(ull& a, ull& b, bool up) {
    ull lo = a < b ? a : b;
    ull hi = a < b ? b : a;
    a = up ? lo : hi;
    b = up ? hi : lo;
}

// ---------------------------------------------------------------------------
// FAT kernel (1024 threads):
//   blocks 0..15  : conflict-free fused-stage bitonic argsort (r14 proven).
//   blocks 16..527: natural-order MFMA zraw = Wd·x; Wd staged f32->bf16 in
//                   LDS (XOR-swizzled, r5 pattern) -> no prep dependency.
// ---------------------------------------------------------------------------
__global__ __launch_bounds__(1024)
void fat_kernel(const float* __restrict__ x,
                const float* __restrict__ coords,
                const float* __restrict__ Wd,
                int* __restrict__ order,
                float* __restrict__ z_pk) {
    extern __shared__ ull skey[];          // 64 KB dynamic
    const int bid = blockIdx.x;
    const int t   = threadIdx.x;

    if (bid < B_) {
        const int b = bid;
        // ---- init pass: morton keys + in-register sort-8 (sizes 2,4,8) ----
        {
            const int i0 = t * 8;
            ull K[8];
            #pragma unroll
            for (int j = 0; j < 8; ++j) {
                const float* c = coords + ((size_t)b * N_ + i0 + j) * 3;
                ull mx = interleave3((ull)quant10(c[0]));
                ull my = interleave3((ull)quant10(c[1]));
                ull mz = interleave3((ull)quant10(c[2]));
                ull m = mx | (my << 1) | (mz << 2);
                K[j] = (m << LOGN) | (ull)(i0 + j);
            }
            cswap(K[0], K[1], true);  cswap(K[2], K[3], false);
            cswap(K[4], K[5], true);  cswap(K[6], K[7], false);
            cswap(K[0], K[2], true);  cswap(K[1], K[3], true);
            cswap(K[4], K[6], false); cswap(K[5], K[7], false);
            cswap(K[0], K[1], true);  cswap(K[2], K[3], true);
            cswap(K[4], K[5], false); cswap(K[6], K[7], false);
            const bool U = ((t & 1) == 0);
            cswap(K[0], K[4], U); cswap(K[1], K[5], U);
            cswap(K[2], K[6], U); cswap(K[3], K[7], U);
            cswap(K[0], K[2], U); cswap(K[1], K[3], U);
            cswap(K[4], K[6], U); cswap(K[5], K[7], U);
            cswap(K[0], K[1], U); cswap(K[2], K[3], U);
            cswap(K[4], K[5], U); cswap(K[6], K[7], U);
            ull2* p2 = (ull2*)&skey[i0];
            #pragma unroll
            for (int j = 0; j < 4; ++j) { ull2 w; w.x = K[2*j]; w.y = K[2*j+1]; p2[j] = w; }
        }
        __syncthreads();

        for (int k = 4; k <= LOGN; ++k) {
            const int size = 1 << k;
            int s = size >> 1;

            while (s >= 32) {
                const int q  = s >> 2;
                const int jj = t & (q - 1);
                const int i0 = ((t - jj) << 3) + jj;
                ull K[8];
                #pragma unroll
                for (int j = 0; j < 8; ++j) K[j] = skey[i0 + j * q];
                const bool up = ((i0 & size) == 0);
                cswap(K[0], K[4], up); cswap(K[1], K[5], up);
                cswap(K[2], K[6], up); cswap(K[3], K[7], up);
                cswap(K[0], K[2], up); cswap(K[1], K[3], up);
                cswap(K[4], K[6], up); cswap(K[5], K[7], up);
                cswap(K[0], K[1], up); cswap(K[2], K[3], up);
                cswap(K[4], K[5], up); cswap(K[6], K[7], up);
                #pragma unroll
                for (int j = 0; j < 8; ++j) skey[i0 + j * q] = K[j];
                __syncthreads();
                s >>= 3;
            }

            if (s == 16) {
                #pragma unroll
                for (int u = 0; u < 2; ++u) {
                    const int p  = t + u * 1024;
                    const int jj = p & 7;
                    const int i0 = ((p - jj) << 2) + jj;
                    ull K0 = skey[i0], K1 = skey[i0 + 8];
                    ull K2 = skey[i0 + 16], K3 = skey[i0 + 24];
                    const bool up = ((i0 & size) == 0);
                    cswap(K0, K2, up); cswap(K1, K3, up);
                    cswap(K0, K1, up); cswap(K2, K3, up);
                    skey[i0] = K0; skey[i0 + 8] = K1;
                    skey[i0 + 16] = K2; skey[i0 + 24] = K3;
                }
                __syncthreads();
            } else if (s == 8) {
                #pragma unroll
                for (int u = 0; u < 4; ++u) {
                    const int p  = t + u * 1024;
                    const int jj = p & 7;
                    const int i  = ((p - jj) << 1) + jj;
                    ull a = skey[i], c = skey[i + 8];
                    cswap(a, c, ((i & size) == 0));
                    skey[i] = a; skey[i + 8] = c;
                }
                __syncthreads();
            }

            {
                const int i0 = t * 8;
                ull K[8];
                ull2* p2 = (ull2*)&skey[i0];
                #pragma unroll
                for (int j = 0; j < 4; ++j) { ull2 w = p2[j]; K[2*j] = w.x; K[2*j+1] = w.y; }
                const bool up = ((i0 & size) == 0);
                cswap(K[0], K[4], up); cswap(K[1], K[5], up);
                cswap(K[2], K[6], up); cswap(K[3], K[7], up);
                cswap(K[0], K[2], up); cswap(K[1], K[3], up);
                cswap(K[4], K[6], up); cswap(K[5], K[7], up);
                cswap(K[0], K[1], up); cswap(K[2], K[3], up);
                cswap(K[4], K[5], up); cswap(K[6], K[7], up);
                if (k == LOGN) {
                    #pragma unroll
                    for (int j = 0; j < 8; ++j)
                        order[b * N_ + i0 + j] = (int)(K[j] & (ull)(N_ - 1));
                } else {
                    #pragma unroll
                    for (int j = 0; j < 4; ++j) { ull2 w; w.x = K[2*j]; w.y = K[2*j+1]; p2[j] = w; }
                    __syncthreads();
                }
            }
        }
    } else {
        // ===== zgemm_nat: 256 rows/block; Wd staged in LDS (bf16, swizzled) =====
        const int zb  = bid - B_;               // 0..511
        const int b   = zb >> 5;
        const int m0  = (zb & 31) << 8;
        const int w   = t >> 6;
        const int l   = t & 63;
        const int lg  = l >> 4;
        const int lm  = l & 15;
        char* wlds = (char*)skey;               // first 16 KB of dynamic LDS

        // stage Wd cols 0..255 -> bf16 [32][256], XOR-swizzled (^ (row&7)<<4)
        {
            const int i0  = t * 8;              // elem index 0..8191
            const int row = i0 >> 8;            // 0..31
            const int col = i0 & 255;
            const float* src = Wd + (size_t)row * 257 + col;
            unsigned off = ((unsigned)row << 9) + ((unsigned)col << 1);
            off ^= (unsigned)(row & 7) << 4;
            ushort4 p0, p1;
            p0.x = f2bf(src[0]); p0.y = f2bf(src[1]);
            p0.z = f2bf(src[2]); p0.w = f2bf(src[3]);
            p1.x = f2bf(src[4]); p1.y = f2bf(src[5]);
            p1.z = f2bf(src[6]); p1.w = f2bf(src[7]);
            *(ushort4*)(wlds + off)     = p0;
            *(ushort4*)(wlds + off + 8) = p1;
        }
        __syncthreads();

        s16x8 wf0[8], wf1[8];
        #pragma unroll
        for (int kc = 0; kc < 8; ++kc) {
            const unsigned doff = (unsigned)(kc * 64 + lg * 16);
            const unsigned sw   = (unsigned)(lm & 7) << 4;
            wf0[kc] = *(const s16x8*)(wlds + ((((unsigned)lm << 9) + doff) ^ sw));
            wf1[kc] = *(const s16x8*)(wlds + ((((unsigned)(16 + lm) << 9) + doff) ^ sw));
        }

        const int xr = w * 16 + lm;
        const float* xrow = x + ((size_t)(b * N_ + m0 + xr)) * D_;

        f32x4 acc0 = {0.f, 0.f, 0.f, 0.f};
        f32x4 acc1 = {0.f, 0.f, 0.f, 0.f};
        #pragma unroll
        for (int kc = 0; kc < 8; ++kc) {
            const float4 va = *(const float4*)(xrow + kc * 32 + lg * 8);
            const float4 vb = *(const float4*)(xrow + kc * 32 + lg * 8 + 4);
            union { s16x8 v; unsigned u[4]; } bu_;
            bu_.u[0] = cvtpk_bf16(va.x, va.y);
            bu_.u[1] = cvtpk_bf16(va.z, va.w);
            bu_.u[2] = cvtpk_bf16(vb.x, vb.y);
            bu_.u[3] = cvtpk_bf16(vb.z, vb.w);
            acc0 = __builtin_amdgcn_mfma_f32_16x16x32_bf16(wf0[kc], bu_.v, acc0, 0, 0, 0);
            acc1 = __builtin_amdgcn_mfma_f32_16x16x32_bf16(wf1[kc], bu_.v, acc1, 0, 0, 0);
        }

        const int m = m0 + xr;
        float* zb_ = z_pk + ((size_t)(b * N_ + m)) * BN_;
        float4 v0, v1;
        v0.x = acc0[0]; v0.y = acc0[1]; v0.z = acc0[2]; v0.w = acc0[3];
        v1.x = acc1[0]; v1.y = acc1[1]; v1.z = acc1[2]; v1.w = acc1[3];
        *(float4*)(zb_ + lg * 4)      = v0;
        *(float4*)(zb_ + 16 + lg * 4) = v1;
    }
}

// ---------------------------------------------------------------------------
// ZG: permutation + radius + bias + relu + transpose to k-major.
// Blocks 0..7 additionally compute G = Wu @ V (consumed later by out).
// ---------------------------------------------------------------------------
__global__ __launch_bounds__(512)
void zgather_kernel(const float* __restrict__ z_pk,
                    const float* __restrict__ coords,
                    const float* __restrict__ Wd,
                    const float* __restrict__ bd,
                    const int*   __restrict__ order,
                    const float* __restrict__ Wu,
                    const float* __restrict__ V,
                    float*       __restrict__ G,
                    float*       __restrict__ z_kp) {
    __shared__ float ltile[64][33];
    __shared__ float sWdLast[BN_];
    __shared__ float sbd[BN_];
    const int blk = blockIdx.x;           // 2048
    const int b   = blk >> 7;
    const int p0  = (blk & 127) << 6;
    const int t   = threadIdx.x;

    // side job: G (8 blocks x 32 d-rows), independent of main body
    if (blk < 8 && t < 128) {
        const int dl = blk * 32 + (t >> 2);
        const int r  = t & 3;
        float s = 0.0f;
        #pragma unroll
        for (int kk = 0; kk < BN_; ++kk) s += Wu[dl * BN_ + kk] * V[kk * R_ + r];
        G[dl * R_ + r] = s;
    }

    if (t < BN_) { sWdLast[t] = Wd[(size_t)t * 257 + 256]; sbd[t] = bd[t]; }
    __syncthreads();

    {
        const int sl = t >> 3;
        const int kc = t & 7;
        const int p  = p0 + sl;
        const int od = order[b * N_ + p];
        float4 v = *(const float4*)(z_pk + ((size_t)(b * N_ + od)) * BN_ + kc * 4);
        const float* c = coords + ((size_t)(b * N_ + p)) * 3;
        const float rr = sqrtf(c[0] * c[0] + c[1] * c[1] + c[2] * c[2]);
        v.x = fmaxf(v.x + rr * sWdLast[kc * 4 + 0] + sbd[kc * 4 + 0], 0.0f);
        v.y = fmaxf(v.y + rr * sWdLast[kc * 4 + 1] + sbd[kc * 4 + 1], 0.0f);
        v.z = fmaxf(v.z + rr * sWdLast[kc * 4 + 2] + sbd[kc * 4 + 2], 0.0f);
        v.w = fmaxf(v.w + rr * sWdLast[kc * 4 + 3] + sbd[kc * 4 + 3], 0.0f);
        ltile[sl][kc * 4 + 0] = v.x;
        ltile[sl][kc * 4 + 1] = v.y;
        ltile[sl][kc * 4 + 2] = v.z;
        ltile[sl][kc * 4 + 3] = v.w;
    }
    __syncthreads();

    {
        const int k  = t >> 4;
        const int pc = t & 15;
        float4 o;
        o.x = ltile[pc * 4 + 0][k];
        o.y = ltile[pc * 4 + 1][k];
        o.z = ltile[pc * 4 + 2][k];
        o.w = ltile[pc * 4 + 3][k];
        *(float4*)(z_kp + (size_t)(b * BN_ + k) * N_ + p0 + pc * 4) = o;
    }
}

// ---------------------------------------------------------------------------
// K4: PAIR-PACKED spectral filter, padded LDS (r15 version).
// ---------------------------------------------------------------------------
__device__ __forceinline__ float2 cmul(float2 a, float2 b) {
    return make_float2(a.x * b.x - a.y * b.y, a.x * b.y + a.y * b.x);
}
__device__ __forceinline__ float2 sdmix(float S, float D, float2 P, float2 Q) {
    return make_float2(S * P.x + D * Q.x, S * P.y - D * Q.y);
}

__global__ __launch_bounds__(512)
void fft_filter_kernel(float* __restrict__ zy,
                       const float* __restrict__ logit_d) {
    extern __shared__ float2 cbuf[];   // 8704 * 8B = 68 KB (padded)

    const int bk = blockIdx.x;     // 256 = B_ * 16
    const int b  = bk >> 4;
    const int kp = bk & 15;
    const int t  = threadIdx.x;

    float* row1 = zy + (size_t)(b * BN_ + 2 * kp) * N_;
    float* row2 = row1 + N_;

    float d1 = fminf(fmaxf(logit_d[2 * kp],     -10.0f), 10.0f);
    float d2 = fminf(fmaxf(logit_d[2 * kp + 1], -10.0f), 10.0f);

    const float cpi  = 3.14159265358979323846f;
    const float c2pi = 6.28318530717958647692f;
    const float A    = c2pi * 8192.0f / 8191.0f;

    const float Eh1 = __expf(-0.5f * A * d1), E1 = Eh1 * Eh1;
    const float Eh2 = __expf(-0.5f * A * d2), E2 = Eh2 * Eh2;

    {
        const int h = 4096, hh = 2048;
        #pragma unroll
        for (int u = 0; u < 4; ++u) {
            const int i0 = t + u * 512;
            float2 c0 = make_float2(row1[i0],            row2[i0]);
            float2 c1 = make_float2(row1[i0 + hh],       row2[i0 + hh]);
            float2 c2 = make_float2(row1[i0 + h],        row2[i0 + h]);
            float2 c3 = make_float2(row1[i0 + h + hh],   row2[i0 + h + hh]);
            float sA, cA;
            __sincosf(-cpi * (float)i0 / (float)h, &sA, &cA);
            const float2 twA1 = make_float2(cA, sA);
            const float2 twA2 = make_float2(sA, -cA);
            const float2 twB  = make_float2(2.0f * cA * cA - 1.0f, 2.0f * sA * cA);
            float2 a0 = make_float2(c0.x + c2.x, c0.y + c2.y);
            float2 a1 = make_float2(c1.x + c3.x, c1.y + c3.y);
            float2 b0 = cmul(make_float2(c0.x - c2.x, c0.y - c2.y), twA1);
            float2 b1 = cmul(make_float2(c1.x - c3.x, c1.y - c3.y), twA2);
            cbuf[PAD(i0)]          = make_float2(a0.x + a1.x, a0.y + a1.y);
            cbuf[PAD(i0 + hh)]     = cmul(make_float2(a0.x - a1.x, a0.y - a1.y), twB);
            cbuf[PAD(i0 + h)]      = make_float2(b0.x + b1.x, b0.y + b1.y);
            cbuf[PAD(i0 + h + hh)] = cmul(make_float2(b0.x - b1.x, b0.y - b1.y), twB);
        }
        __syncthreads();
    }

    #pragma unroll
    for (int h = 1024; h >= 4; h >>= 2) {
        const int hh = h >> 1;
        #pragma unroll
        for (int u = 0; u < 4; ++u) {
            const int q   = t + u * 512;
            const int jj  = q & (hh - 1);
            const int i0  = ((q - jj) << 2) + jj;
            float2 c0 = cbuf[PAD(i0)];
            float2 c1 = cbuf[PAD(i0 + hh)];
            float2 c2 = cbuf[PAD(i0 + h)];
            float2 c3 = cbuf[PAD(i0 + h + hh)];
            float sA, cA;
            __sincosf(-cpi * (float)jj / (float)h, &sA, &cA);
            const float2 twA1 = make_float2(cA, sA);
            const float2 twA2 = make_float2(sA, -cA);
            const float2 twB  = make_float2(2.0f * cA * cA - 1.0f, 2.0f * sA * cA);
            float2 a0 = make_float2(c0.x + c2.x, c0.y + c2.y);
            float2 a1 = make_float2(c1.x + c3.x, c1.y + c3.y);
            float2 b0 = cmul(make_float2(c0.x - c2.x, c0.y - c2.y), twA1);
            float2 b1 = cmul(make_float2(c1.x - c3.x, c1.y - c3.y), twA2);
            cbuf[PAD(i0)]          = make_float2(a0.x + a1.x, a0.y + a1.y);
            cbuf[PAD(i0 + hh)]     = cmul(make_float2(a0.x - a1.x, a0.y - a1.y), twB);
            cbuf[PAD(i0 + h)]      = make_float2(b0.x + b1.x, b0.y + b1.y);
            cbuf[PAD(i0 + h + hh)] = cmul(make_float2(b0.x - b1.x, b0.y - b1.y), twB);
        }
        __syncthreads();
    }

    {
        #pragma unroll
        for (int v = 0; v < 4; ++v) {
            const int u = t + v * 512;
            if (u == 0) {
                {
                    float2 g0 = cbuf[0], g1 = cbuf[1];
                    float2 Pa = make_float2(g0.x + g1.x, g0.y + g1.y);
                    float2 Pb = make_float2(g0.x - g1.x, g0.y - g1.y);
                    float2 Ra = Pa;
                    float Sb = 0.5f * (Eh1 + Eh2), Db = 0.5f * (Eh1 - Eh2);
                    float2 Rb = sdmix(Sb, Db, Pb, Pb);
                    cbuf[0] = make_float2(Ra.x + Rb.x, Ra.y + Rb.y);
                    cbuf[1] = make_float2(Ra.x - Rb.x, Ra.y - Rb.y);
                }
                {
                    float wu = c2pi * 2048.0f / 8191.0f;
                    float h1 = __expf(-wu * d1), h2 = __expf(-wu * d2);
                    float h1b = h1 * Eh1, h2b = h2 * Eh2;
                    float Hs1a = 0.5f * (h1 + E1 / h1);
                    float Hs2a = 0.5f * (h2 + E2 / h2);
                    float Hs1b = 0.5f * (h1b + E1 / h1b);
                    float Hs2b = 0.5f * (h2b + E2 / h2b);
                    float Sa = 0.5f * (Hs1a + Hs2a), Da = 0.5f * (Hs1a - Hs2a);
                    float Sb = 0.5f * (Hs1b + Hs2b), Db = 0.5f * (Hs1b - Hs2b);
                    float2 g0 = cbuf[2], g1 = cbuf[3];
                    float2 Pa = make_float2(g0.x + g1.x, g0.y + g1.y);
                    float2 Pb = make_float2(g0.x - g1.x, g0.y - g1.y);
                    float2 Ra = sdmix(Sa, Da, Pa, Pb);
                    float2 Rb = sdmix(Sb, Db, Pb, Pa);
                    cbuf[2] = make_float2(Ra.x + Rb.x, Ra.y + Rb.y);
                    cbuf[3] = make_float2(Ra.x - Rb.x, Ra.y - Rb.y);
                }
            } else {
                const int u2 = 4096 - u;
                const int c  = (int)(__brev((unsigned)u)  >> 20);
                const int c2 = (int)(__brev((unsigned)u2) >> 20);
                const int s0 = PAD(2 * c),  s1 = PAD(2 * c + 1);
                const int s2 = PAD(2 * c2), s3 = PAD(2 * c2 + 1);
                float2 g0 = cbuf[s0], g1 = cbuf[s1];
                float2 q0 = cbuf[s2], q1 = cbuf[s3];
                float2 Pa  = make_float2(g0.x + g1.x, g0.y + g1.y);
                float2 Pb  = make_float2(g0.x - g1.x, g0.y - g1.y);
                float2 Pa2 = make_float2(q0.x + q1.x, q0.y + q1.y);
                float2 Pb2 = make_float2(q0.x - q1.x, q0.y - q1.y);
                float wu = c2pi * (float)u / 8191.0f;
                float h1 = __expf(-wu * d1), h2 = __expf(-wu * d2);
                float h1b = h1 * Eh1, h2b = h2 * Eh2;
                float Hs1a = 0.5f * (h1 + E1 / h1);
                float Hs2a = 0.5f * (h2 + E2 / h2);
                float Hs1b = 0.5f * (h1b + E1 / h1b);
                float Hs2b = 0.5f * (h2b + E2 / h2b);
                float Sa = 0.5f * (Hs1a + Hs2a), Da = 0.5f * (Hs1a - Hs2a);
                float Sb = 0.5f * (Hs1b + Hs2b), Db = 0.5f * (Hs1b - Hs2b);
                float2 Ra  = sdmix(Sa, Da, Pa,  Pb2);
                float2 Rb2 = sdmix(Sa, Da, Pb2, Pa);
                float2 Rb  = sdmix(Sb, Db, Pb,  Pa2);
                float2 Ra2 = sdmix(Sb, Db, Pa2, Pb);
                cbuf[s0] = make_float2(Ra.x + Rb.x,   Ra.y + Rb.y);
                cbuf[s1] = make_float2(Ra.x - Rb.x,   Ra.y - Rb.y);
                cbuf[s2] = make_float2(Ra2.x + Rb2.x, Ra2.y + Rb2.y);
                cbuf[s3] = make_float2(Ra2.x - Rb2.x, Ra2.y - Rb2.y);
            }
        }
        __syncthreads();
    }

    #pragma unroll
    for (int h = 2; h <= 512; h <<= 2) {
        #pragma unroll
        for (int u = 0; u < 4; ++u) {
            const int q  = t + u * 512;
            const int jj = q & (h - 1);
            const int i0 = ((q - jj) << 2) + jj;
            float2 c0 = cbuf[PAD(i0)];
            float2 c1 = cbuf[PAD(i0 + h)];
            float2 c2 = cbuf[PAD(i0 + 2 * h)];
            float2 c3 = cbuf[PAD(i0 + 3 * h)];
            float sa, ca;
            __sincosf(cpi * (float)jj / (float)(2 * h), &sa, &ca);
            const float2 tw1  = make_float2(2.0f * ca * ca - 1.0f, 2.0f * sa * ca);
            const float2 tw2a = make_float2(ca, sa);
            const float2 tw2b = make_float2(-sa, ca);
            float2 t0 = cmul(c1, tw1);
            float2 a0 = make_float2(c0.x + t0.x, c0.y + t0.y);
            float2 a1 = make_float2(c0.x - t0.x, c0.y - t0.y);
            float2 t1 = cmul(c3, tw1);
            float2 b0 = make_float2(c2.x + t1.x, c2.y + t1.y);
            float2 b1 = make_float2(c2.x - t1.x, c2.y - t1.y);
            float2 t2 = cmul(b0, tw2a);
            cbuf[PAD(i0)]         = make_float2(a0.x + t2.x, a0.y + t2.y);
            cbuf[PAD(i0 + 2 * h)] = make_float2(a0.x - t2.x, a0.y - t2.y);
            float2 t3 = cmul(b1, tw2b);
            cbuf[PAD(i0 + h)]     = make_float2(a1.x + t3.x, a1.y + t3.y);
            cbuf[PAD(i0 + 3 * h)] = make_float2(a1.x - t3.x, a1.y - t3.y);
        }
        __syncthreads();
    }

    {
        const int h = 2048;
        const float inv = 1.0f / (float)N_;
        #pragma unroll
        for (int u = 0; u < 4; ++u) {
            const int jj = t + u * 512;
            const int i0 = jj;
            float2 c0 = cbuf[PAD(i0)];
            float2 c1 = cbuf[PAD(i0 + h)];
            float2 c2 = cbuf[PAD(i0 + 2 * h)];
            float2 c3 = cbuf[PAD(i0 + 3 * h)];
            float sa, ca;
            __sincosf(cpi * (float)jj / (float)(2 * h), &sa, &ca);
            const float2 tw1  = make_float2(2.0f * ca * ca - 1.0f, 2.0f * sa * ca);
            const float2 tw2a = make_float2(ca, sa);
            const float2 tw2b = make_float2(-sa, ca);
            float2 t0 = cmul(c1, tw1);
            float2 a0 = make_float2(c0.x + t0.x, c0.y + t0.y);
            float2 a1 = make_float2(c0.x - t0.x, c0.y - t0.y);
            float2 t1 = cmul(c3, tw1);
            float2 b0 = make_float2(c2.x + t1.x, c2.y + t1.y);
            float2 b1 = make_float2(c2.x - t1.x, c2.y - t1.y);
            float2 t2 = cmul(b0, tw2a);
            float2 o0 = make_float2(a0.x + t2.x, a0.y + t2.y);
            float2 o2 = make_float2(a0.x - t2.x, a0.y - t2.y);
            float2 t3 = cmul(b1, tw2b);
            float2 o1 = make_float2(a1.x + t3.x, a1.y + t3.y);
            float2 o3 = make_float2(a1.x - t3.x, a1.y - t3.y);
            row1[i0]         = o0.x * inv;  row2[i0]         = o0.y * inv;
            row1[i0 + h]     = o1.x * inv;  row2[i0 + h]     = o1.y * inv;
            row1[i0 + 2*h]   = o2.x * inv;  row2[i0 + 2*h]   = o2.y * inv;
            row1[i0 + 3*h]   = o3.x * inv;  row2[i0 + 3*h]   = o3.y * inv;
        }
    }
}

// ---------------------------------------------------------------------------
// K5: t[b,n,r] = sum_k y[b,k,n]·U[k,r];  out = x + t @ G^T + bu (r15 ver).
// ---------------------------------------------------------------------------
__global__ __launch_bounds__(256)
void out_kernel(const float* __restrict__ x,
                const float* __restrict__ y_t,
                const float* __restrict__ U,
                const float* __restrict__ G,
                const float* __restrict__ bu,
                float*       __restrict__ out) {
    __shared__ float ttile[64][R_ + 1];
    const int blk = blockIdx.x;          // 2048
    const int b   = blk >> 7;
    const int n0  = (blk & 127) << 6;
    const int t   = threadIdx.x;

    {
        const int r = t >> 6, nl = t & 63;
        const float* yb = y_t + (size_t)b * BN_ * N_ + n0 + nl;
        float s = 0.0f;
        #pragma unroll
        for (int kk = 0; kk < BN_; ++kk) s += yb[(size_t)kk * N_] * U[kk * R_ + r];
        ttile[nl][r] = s;
    }
    __syncthreads();

    const int d4 = t & 63, rg = t >> 6;
    const float4 g0 = *(const float4*)(G + (d4 * 4 + 0) * 4);
    const float4 g1 = *(const float4*)(G + (d4 * 4 + 1) * 4);
    const float4 g2 = *(const float4*)(G + (d4 * 4 + 2) * 4);
    const float4 g3 = *(const float4*)(G + (d4 * 4 + 3) * 4);
    const float4 bv = *(const float4*)(bu + d4 * 4);
    const float4* xb = (const float4*)(x   + ((size_t)(b * N_ + n0)) * D_);
    float4*       ob = (float4*)      (out + ((size_t)(b * N_ + n0)) * D_);
    #pragma unroll 4
    for (int nl = rg; nl < 64; nl += 4) {
        const float t0 = ttile[nl][0], t1 = ttile[nl][1];
        const float t2 = ttile[nl][2], t3 = ttile[nl][3];
        const float4 xv = xb[nl * 64 + d4];
        float4 o;
        o.x = xv.x + t0 * g0.x + t1 * g0.y + t2 * g0.z + t3 * g0.w + bv.x;
        o.y = xv.y + t0 * g1.x + t1 * g1.y + t2 * g1.z + t3 * g1.w + bv.y;
        o.z = xv.z + t0 * g2.x + t1 * g2.y + t2 * g2.z + t3 * g2.w + bv.z;
        o.w = xv.w + t0 * g3.x + t1 * g3.y + t2 * g3.z + t3 * g3.w + bv.w;
        ob[nl * 64 + d4] = o;
    }
}

// ---------------------------------------------------------------------------
extern "C" void kernel_launch(void* const* d_in, const int* in_sizes, int n_in,
                              void* d_out, int out_size, void* d_ws, size_t ws_size,
                              hipStream_t stream) {
    const float* x       = (const float*)d_in[0];
    const float* coords  = (const float*)d_in[1];
    const float* Wd      = (const float*)d_in[2];
    const float* bd      = (const float*)d_in[3];
    const float* U       = (const float*)d_in[4];
    const float* V       = (const float*)d_in[5];
    const float* logit_d = (const float*)d_in[6];
    const float* Wu      = (const float*)d_in[7];
    const float* bu      = (const float*)d_in[8];
    float* out = (float*)d_out;

    char* ws = (char*)d_ws;
    int*   order = (int*)ws;                             // 512 KB
    float* G     = (float*)(ws + 1536 * 1024);           // 4 KB
    float* zpk   = (float*)(ws + 2048 * 1024);           // 16 MB
    float* zkp   = (float*)(ws + (2048 + 16384) * 1024); // 16 MB

    fat_kernel   <<<dim3(B_ + 512),    dim3(1024), 64 * 1024, stream>>>(x, coords, Wd, order, zpk);
    zgather_kernel<<<dim3(B_ * 128),   dim3(512),  0, stream>>>(zpk, coords, Wd, bd, order, Wu, V, G, zkp);
    fft_filter_kernel<<<dim3(B_ * 16), dim3(512),  8704 * 8, stream>>>(zkp, logit_d);
    out_kernel   <<<dim3(B_ * 128),    dim3(256),  0, stream>>>(x, zkp, U, G, bu, out);
}

// Round 17
// 118.401 us; speedup vs baseline: 1.3706x; 1.1404x over previous
//
#include <hip/hip_runtime.h>
#include <math.h>

#define B_    16
#define N_    8192
#define D_    256
#define BN_   32
#define R_    4
#define LOGN  13

typedef float  f32x4  __attribute__((ext_vector_type(4)));
typedef short  s16x8  __attribute__((ext_vector_type(8)));
typedef unsigned long long ull;
typedef ull    ull2   __attribute__((ext_vector_type(2)));

// FFT LDS pad: i -> i + i/16 (8B elems). 8191 -> 8702 (68 KB).
__device__ __forceinline__ int PAD(int i) { return i + (i >> 4); }

// ---------------------------------------------------------------------------
// Morton helpers (exact replica of reference bit-interleave)
// ---------------------------------------------------------------------------
__device__ __forceinline__ ull interleave3(ull v) {
    v = v & 2097151ULL;
    v = v | (v << 32);
    v = v & 8725724278095871ULL;
    v = v | ((v << 16) & 8725728556220671ULL);
    v = v | ((v << 8)  & 282506020581391ULL);
    v = v | ((v << 4)  & 294878547030211ULL);
    v = v | ((v << 2)  & 321685687669321ULL);
    return v;
}

__device__ __forceinline__ long long quant10(float c) {
    long long v = (long long)(c * 1023.0f);
    v = v < 0 ? 0 : (v > 1023 ? 1023 : v);
    return v;
}

__device__ __forceinline__ unsigned short f2bf(float f) {
    unsigned u = __float_as_uint(f);
    u = (u + 0x7FFF + ((u >> 16) & 1)) >> 16;   // RNE
    return (unsigned short)u;
}

__device__ __forceinline__ unsigned cvtpk_bf16(float lo, float hi) {
    unsigned r;
    asm("v_cvt_pk_bf16_f32 %0, %1, %2" : "=v"(r) : "v"(lo), "v"(hi));
    return r;
}

__device__ __forceinline__ void cswap(ull& a, ull& b, bool up) {
    ull lo = a < b ? a : b;
    ull hi = a < b ? b : a;
    a = up ? lo : hi;
    b = up ? hi : lo;
}

// ---------------------------------------------------------------------------
// FAT kernel (512 threads):
//   blocks 0..31   : sort1 — fused-stage bitonic on 4096 keys (one half-batch),
//                    sizes 2..4096, direction from GLOBAL index; conflict-free
//                    pass shapes (TRIPLE/DOUBLE/SINGLE/CONTIG). Emits keys[].
//   blocks 32..1055: natural-order MFMA zraw = Wd·x, 128 rows/block; Wd staged
//                    f32->bf16 in LDS (XOR-swizzled); direct global->reg B.
// ---------------------------------------------------------------------------
__global__ __launch_bounds__(512)
void fat_kernel(const float* __restrict__ x,
                const float* __restrict__ coords,
                const float* __restrict__ Wd,
                ull* __restrict__ keys,
                float* __restrict__ z_pk) {
    extern __shared__ ull skey[];          // 32 KB dynamic
    const int bid = blockIdx.x;
    const int t   = threadIdx.x;

    if (bid < 2 * B_) {
        const int b = bid >> 1;
        const int h = bid & 1;
        const int gbase = h * 4096;

        // ---- init: morton keys + in-register sort-8 (sizes 2,4,8) ----
        {
            const int i0 = t * 8;              // local 0..4088
            ull K[8];
            #pragma unroll
            for (int j = 0; j < 8; ++j) {
                const int gi = gbase + i0 + j;
                const float* c = coords + ((size_t)b * N_ + gi) * 3;
                ull mx = interleave3((ull)quant10(c[0]));
                ull my = interleave3((ull)quant10(c[1]));
                ull mz = interleave3((ull)quant10(c[2]));
                ull m = mx | (my << 1) | (mz << 2);
                K[j] = (m << LOGN) | (ull)gi;
            }
            cswap(K[0], K[1], true);  cswap(K[2], K[3], false);
            cswap(K[4], K[5], true);  cswap(K[6], K[7], false);
            cswap(K[0], K[2], true);  cswap(K[1], K[3], true);
            cswap(K[4], K[6], false); cswap(K[5], K[7], false);
            cswap(K[0], K[1], true);  cswap(K[2], K[3], true);
            cswap(K[4], K[5], false); cswap(K[6], K[7], false);
            const bool U = ((t & 1) == 0);
            cswap(K[0], K[4], U); cswap(K[1], K[5], U);
            cswap(K[2], K[6], U); cswap(K[3], K[7], U);
            cswap(K[0], K[2], U); cswap(K[1], K[3], U);
            cswap(K[4], K[6], U); cswap(K[5], K[7], U);
            cswap(K[0], K[1], U); cswap(K[2], K[3], U);
            cswap(K[4], K[5], U); cswap(K[6], K[7], U);
            ull2* p2 = (ull2*)&skey[i0];
            #pragma unroll
            for (int j = 0; j < 4; ++j) { ull2 w; w.x = K[2*j]; w.y = K[2*j+1]; p2[j] = w; }
        }
        __syncthreads();

        // ---- phases size = 16 .. 4096 ----
        for (int k = 4; k <= 12; ++k) {
            const int size = 1 << k;
            int s = size >> 1;

            while (s >= 32) {                  // TRIPLE {s, s/2, s/4}, q >= 8
                const int q  = s >> 2;
                const int jj = t & (q - 1);
                const int i0 = ((t - jj) << 3) + jj;
                ull K[8];
                #pragma unroll
                for (int j = 0; j < 8; ++j) K[j] = skey[i0 + j * q];
                const bool up = (((gbase + i0) & size) == 0);
                cswap(K[0], K[4], up); cswap(K[1], K[5], up);
                cswap(K[2], K[6], up); cswap(K[3], K[7], up);
                cswap(K[0], K[2], up); cswap(K[1], K[3], up);
                cswap(K[4], K[6], up); cswap(K[5], K[7], up);
                cswap(K[0], K[1], up); cswap(K[2], K[3], up);
                cswap(K[4], K[5], up); cswap(K[6], K[7], up);
                #pragma unroll
                for (int j = 0; j < 8; ++j) skey[i0 + j * q] = K[j];
                __syncthreads();
                s >>= 3;
            }

            if (s == 16) {                     // DOUBLE {16, 8}
                #pragma unroll
                for (int u = 0; u < 2; ++u) {
                    const int p  = t + u * 512;          // 1024 groups of 4
                    const int jj = p & 7;
                    const int i0 = ((p - jj) << 2) + jj;
                    ull K0 = skey[i0], K1 = skey[i0 + 8];
                    ull K2 = skey[i0 + 16], K3 = skey[i0 + 24];
                    const bool up = (((gbase + i0) & size) == 0);
                    cswap(K0, K2, up); cswap(K1, K3, up);
                    cswap(K0, K1, up); cswap(K2, K3, up);
                    skey[i0] = K0; skey[i0 + 8] = K1;
                    skey[i0 + 16] = K2; skey[i0 + 24] = K3;
                }
                __syncthreads();
            } else if (s == 8) {               // SINGLE {8}
                #pragma unroll
                for (int u = 0; u < 4; ++u) {
                    const int p  = t + u * 512;          // 2048 pairs
                    const int jj = p & 7;
                    const int i  = ((p - jj) << 1) + jj;
                    ull a = skey[i], c = skey[i + 8];
                    cswap(a, c, (((gbase + i) & size) == 0));
                    skey[i] = a; skey[i + 8] = c;
                }
                __syncthreads();
            }

            // CONTIG {4,2,1} on thread-owned 8 consecutive (b128 I/O)
            {
                const int i0 = t * 8;
                ull K[8];
                ull2* p2 = (ull2*)&skey[i0];
                #pragma unroll
                for (int j = 0; j < 4; ++j) { ull2 w = p2[j]; K[2*j] = w.x; K[2*j+1] = w.y; }
                const bool up = (((gbase + i0) & size) == 0);
                cswap(K[0], K[4], up); cswap(K[1], K[5], up);
                cswap(K[2], K[6], up); cswap(K[3], K[7], up);
                cswap(K[0], K[2], up); cswap(K[1], K[3], up);
                cswap(K[4], K[6], up); cswap(K[5], K[7], up);
                cswap(K[0], K[1], up); cswap(K[2], K[3], up);
                cswap(K[4], K[5], up); cswap(K[6], K[7], up);
                if (k == 12) {
                    // half fully sorted (dir from global idx) -> emit to global
                    #pragma unroll
                    for (int j = 0; j < 8; ++j)
                        keys[(size_t)b * N_ + gbase + i0 + j] = K[j];
                } else {
                    #pragma unroll
                    for (int j = 0; j < 4; ++j) { ull2 w; w.x = K[2*j]; w.y = K[2*j+1]; p2[j] = w; }
                    __syncthreads();
                }
            }
        }
    } else {
        // ===== zgemm_nat: 128 rows/block; Wd staged in LDS (bf16, swizzled) =====
        const int zb  = bid - 2 * B_;           // 0..1023
        const int b   = zb >> 6;
        const int m0  = (zb & 63) << 7;         // 128-row tile base
        const int w   = t >> 6;                 // 0..7
        const int l   = t & 63;
        const int lg  = l >> 4;
        const int lm  = l & 15;
        char* wlds = (char*)skey;               // first 16 KB

        // stage Wd cols 0..255 -> bf16 [32][256], XOR-swizzled (^ (row&7)<<4)
        {
            const int i0  = t * 16;             // elem index, 16 per thread
            const int row = i0 >> 8;
            const int col = i0 & 255;
            const float* src = Wd + (size_t)row * 257 + col;
            const unsigned sw   = (unsigned)(row & 7) << 4;
            const unsigned base = ((unsigned)row << 9) + ((unsigned)col << 1);
            ushort4 a0, a1, b0, b1;
            a0.x = f2bf(src[0]);  a0.y = f2bf(src[1]);
            a0.z = f2bf(src[2]);  a0.w = f2bf(src[3]);
            a1.x = f2bf(src[4]);  a1.y = f2bf(src[5]);
            a1.z = f2bf(src[6]);  a1.w = f2bf(src[7]);
            b0.x = f2bf(src[8]);  b0.y = f2bf(src[9]);
            b0.z = f2bf(src[10]); b0.w = f2bf(src[11]);
            b1.x = f2bf(src[12]); b1.y = f2bf(src[13]);
            b1.z = f2bf(src[14]); b1.w = f2bf(src[15]);
            const unsigned o0 = base ^ sw;
            const unsigned o1 = (base + 16) ^ sw;
            *(ushort4*)(wlds + o0)     = a0;
            *(ushort4*)(wlds + o0 + 8) = a1;
            *(ushort4*)(wlds + o1)     = b0;
            *(ushort4*)(wlds + o1 + 8) = b1;
        }
        __syncthreads();

        s16x8 wf0[8], wf1[8];
        #pragma unroll
        for (int kc = 0; kc < 8; ++kc) {
            const unsigned doff = (unsigned)(kc * 64 + lg * 16);
            const unsigned swA  = (unsigned)(lm & 7) << 4;
            wf0[kc] = *(const s16x8*)(wlds + ((((unsigned)lm << 9) + doff) ^ swA));
            wf1[kc] = *(const s16x8*)(wlds + ((((unsigned)(16 + lm) << 9) + doff) ^ swA));
        }

        const int xr = w * 16 + lm;             // row within tile (0..127)
        const float* xrow = x + ((size_t)(b * N_ + m0 + xr)) * D_;

        f32x4 acc0 = {0.f, 0.f, 0.f, 0.f};
        f32x4 acc1 = {0.f, 0.f, 0.f, 0.f};
        #pragma unroll
        for (int kc = 0; kc < 8; ++kc) {
            const float4 va = *(const float4*)(xrow + kc * 32 + lg * 8);
            const float4 vb = *(const float4*)(xrow + kc * 32 + lg * 8 + 4);
            union { s16x8 v; unsigned u[4]; } bu_;
            bu_.u[0] = cvtpk_bf16(va.x, va.y);
            bu_.u[1] = cvtpk_bf16(va.z, va.w);
            bu_.u[2] = cvtpk_bf16(vb.x, vb.y);
            bu_.u[3] = cvtpk_bf16(vb.z, vb.w);
            acc0 = __builtin_amdgcn_mfma_f32_16x16x32_bf16(wf0[kc], bu_.v, acc0, 0, 0, 0);
            acc1 = __builtin_amdgcn_mfma_f32_16x16x32_bf16(wf1[kc], bu_.v, acc1, 0, 0, 0);
        }

        const int m = m0 + xr;
        float* zb_ = z_pk + ((size_t)(b * N_ + m)) * BN_;
        float4 v0, v1;
        v0.x = acc0[0]; v0.y = acc0[1]; v0.z = acc0[2]; v0.w = acc0[3];
        v1.x = acc1[0]; v1.y = acc1[1]; v1.z = acc1[2]; v1.w = acc1[3];
        *(float4*)(zb_ + lg * 4)      = v0;
        *(float4*)(zb_ + 16 + lg * 4) = v1;
    }
}

// ---------------------------------------------------------------------------
// S2: final bitonic merge (size 8192). 32 blocks (b, half), 512 threads.
// Load performs global stride-4096 min/max; then fused strides 2048..1
// (all ascending) in 4 LDS passes; CONTIG pass emits order directly.
// ---------------------------------------------------------------------------
__global__ __launch_bounds__(512)
void sort2_kernel(const ull* __restrict__ keys, int* __restrict__ order) {
    __shared__ ull skey[4096];    // 32 KB
    const int b = blockIdx.x >> 1;
    const int h = blockIdx.x & 1;
    const int t = threadIdx.x;
    const int gbase = h * 4096;

    for (int i = t; i < 4096; i += 512) {
        ull a = keys[(size_t)b * N_ + i];
        ull c = keys[(size_t)b * N_ + 4096 + i];
        ull lo = a < c ? a : c;
        ull hi = a < c ? c : a;
        skey[i] = h == 0 ? lo : hi;
    }
    __syncthreads();

    // TRIPLE passes: q = 512, 64, 8  (strides {2048,1024,512},{256,128,64},{32,16,8})
    #pragma unroll
    for (int q = 512; q >= 8; q >>= 3) {
        const int jj = t & (q - 1);
        const int i0 = ((t - jj) << 3) + jj;
        ull K[8];
        #pragma unroll
        for (int j = 0; j < 8; ++j) K[j] = skey[i0 + j * q];
        cswap(K[0], K[4], true); cswap(K[1], K[5], true);
        cswap(K[2], K[6], true); cswap(K[3], K[7], true);
        cswap(K[0], K[2], true); cswap(K[1], K[3], true);
        cswap(K[4], K[6], true); cswap(K[5], K[7], true);
        cswap(K[0], K[1], true); cswap(K[2], K[3], true);
        cswap(K[4], K[5], true); cswap(K[6], K[7], true);
        #pragma unroll
        for (int j = 0; j < 8; ++j) skey[i0 + j * q] = K[j];
        __syncthreads();
    }

    // CONTIG {4,2,1} + emit
    {
        const int i0 = t * 8;
        ull K[8];
        ull2* p2 = (ull2*)&skey[i0];
        #pragma unroll
        for (int j = 0; j < 4; ++j) { ull2 w = p2[j]; K[2*j] = w.x; K[2*j+1] = w.y; }
        cswap(K[0], K[4], true); cswap(K[1], K[5], true);
        cswap(K[2], K[6], true); cswap(K[3], K[7], true);
        cswap(K[0], K[2], true); cswap(K[1], K[3], true);
        cswap(K[4], K[6], true); cswap(K[5], K[7], true);
        cswap(K[0], K[1], true); cswap(K[2], K[3], true);
        cswap(K[4], K[5], true); cswap(K[6], K[7], true);
        #pragma unroll
        for (int j = 0; j < 8; ++j)
            order[b * N_ + gbase + i0 + j] = (int)(K[j] & (ull)(N_ - 1));
    }
}

// ---------------------------------------------------------------------------
// ZG: permutation + radius + bias + relu + transpose to k-major.
// Blocks 0..7 additionally compute G = Wu @ V.
// ---------------------------------------------------------------------------
__global__ __launch_bounds__(512)
void zgather_kernel(const float* __restrict__ z_pk,
                    const float* __restrict__ coords,
                    const float* __restrict__ Wd,
                    const float* __restrict__ bd,
                    const int*   __restrict__ order,
                    const float* __restrict__ Wu,
                    const float* __restrict__ V,
                    float*       __restrict__ G,
                    float*       __restrict__ z_kp) {
    __shared__ float ltile[64][33];
    __shared__ float sWdLast[BN_];
    __shared__ float sbd[BN_];
    const int blk = blockIdx.x;           // 2048
    const int b   = blk >> 7;
    const int p0  = (blk & 127) << 6;
    const int t   = threadIdx.x;

    if (blk < 8 && t < 128) {
        const int dl = blk * 32 + (t >> 2);
        const int r  = t & 3;
        float s = 0.0f;
        #pragma unroll
        for (int kk = 0; kk < BN_; ++kk) s += Wu[dl * BN_ + kk] * V[kk * R_ + r];
        G[dl * R_ + r] = s;
    }

    if (t < BN_) { sWdLast[t] = Wd[(size_t)t * 257 + 256]; sbd[t] = bd[t]; }
    __syncthreads();

    {
        const int sl = t >> 3;
        const int kc = t & 7;
        const int p  = p0 + sl;
        const int od = order[b * N_ + p];
        float4 v = *(const float4*)(z_pk + ((size_t)(b * N_ + od)) * BN_ + kc * 4);
        const float* c = coords + ((size_t)(b * N_ + p)) * 3;
        const float rr = sqrtf(c[0] * c[0] + c[1] * c[1] + c[2] * c[2]);
        v.x = fmaxf(v.x + rr * sWdLast[kc * 4 + 0] + sbd[kc * 4 + 0], 0.0f);
        v.y = fmaxf(v.y + rr * sWdLast[kc * 4 + 1] + sbd[kc * 4 + 1], 0.0f);
        v.z = fmaxf(v.z + rr * sWdLast[kc * 4 + 2] + sbd[kc * 4 + 2], 0.0f);
        v.w = fmaxf(v.w + rr * sWdLast[kc * 4 + 3] + sbd[kc * 4 + 3], 0.0f);
        ltile[sl][kc * 4 + 0] = v.x;
        ltile[sl][kc * 4 + 1] = v.y;
        ltile[sl][kc * 4 + 2] = v.z;
        ltile[sl][kc * 4 + 3] = v.w;
    }
    __syncthreads();

    {
        const int k  = t >> 4;
        const int pc = t & 15;
        float4 o;
        o.x = ltile[pc * 4 + 0][k];
        o.y = ltile[pc * 4 + 1][k];
        o.z = ltile[pc * 4 + 2][k];
        o.w = ltile[pc * 4 + 3][k];
        *(float4*)(z_kp + (size_t)(b * BN_ + k) * N_ + p0 + pc * 4) = o;
    }
}

// ---------------------------------------------------------------------------
// K4: PAIR-PACKED spectral filter, padded LDS (r15 version).
// ---------------------------------------------------------------------------
__device__ __forceinline__ float2 cmul(float2 a, float2 b) {
    return make_float2(a.x * b.x - a.y * b.y, a.x * b.y + a.y * b.x);
}
__device__ __forceinline__ float2 sdmix(float S, float D, float2 P, float2 Q) {
    return make_float2(S * P.x + D * Q.x, S * P.y - D * Q.y);
}

__global__ __launch_bounds__(512)
void fft_filter_kernel(float* __restrict__ zy,
                       const float* __restrict__ logit_d) {
    extern __shared__ float2 cbuf[];   // 8704 * 8B = 68 KB (padded)

    const int bk = blockIdx.x;     // 256 = B_ * 16
    const int b  = bk >> 4;
    const int kp = bk & 15;
    const int t  = threadIdx.x;

    float* row1 = zy + (size_t)(b * BN_ + 2 * kp) * N_;
    float* row2 = row1 + N_;

    float d1 = fminf(fmaxf(logit_d[2 * kp],     -10.0f), 10.0f);
    float d2 = fminf(fmaxf(logit_d[2 * kp + 1], -10.0f), 10.0f);

    const float cpi  = 3.14159265358979323846f;
    const float c2pi = 6.28318530717958647692f;
    const float A    = c2pi * 8192.0f / 8191.0f;

    const float Eh1 = __expf(-0.5f * A * d1), E1 = Eh1 * Eh1;
    const float Eh2 = __expf(-0.5f * A * d2), E2 = Eh2 * Eh2;

    {
        const int h = 4096, hh = 2048;
        #pragma unroll
        for (int u = 0; u < 4; ++u) {
            const int i0 = t + u * 512;
            float2 c0 = make_float2(row1[i0],            row2[i0]);
            float2 c1 = make_float2(row1[i0 + hh],       row2[i0 + hh]);
            float2 c2 = make_float2(row1[i0 + h],        row2[i0 + h]);
            float2 c3 = make_float2(row1[i0 + h + hh],   row2[i0 + h + hh]);
            float sA, cA;
            __sincosf(-cpi * (float)i0 / (float)h, &sA, &cA);
            const float2 twA1 = make_float2(cA, sA);
            const float2 twA2 = make_float2(sA, -cA);
            const float2 twB  = make_float2(2.0f * cA * cA - 1.0f, 2.0f * sA * cA);
            float2 a0 = make_float2(c0.x + c2.x, c0.y + c2.y);
            float2 a1 = make_float2(c1.x + c3.x, c1.y + c3.y);
            float2 b0 = cmul(make_float2(c0.x - c2.x, c0.y - c2.y), twA1);
            float2 b1 = cmul(make_float2(c1.x - c3.x, c1.y - c3.y), twA2);
            cbuf[PAD(i0)]          = make_float2(a0.x + a1.x, a0.y + a1.y);
            cbuf[PAD(i0 + hh)]     = cmul(make_float2(a0.x - a1.x, a0.y - a1.y), twB);
            cbuf[PAD(i0 + h)]      = make_float2(b0.x + b1.x, b0.y + b1.y);
            cbuf[PAD(i0 + h + hh)] = cmul(make_float2(b0.x - b1.x, b0.y - b1.y), twB);
        }
        __syncthreads();
    }

    #pragma unroll
    for (int h = 1024; h >= 4; h >>= 2) {
        const int hh = h >> 1;
        #pragma unroll
        for (int u = 0; u < 4; ++u) {
            const int q   = t + u * 512;
            const int jj  = q & (hh - 1);
            const int i0  = ((q - jj) << 2) + jj;
            float2 c0 = cbuf[PAD(i0)];
            float2 c1 = cbuf[PAD(i0 + hh)];
            float2 c2 = cbuf[PAD(i0 + h)];
            float2 c3 = cbuf[PAD(i0 + h + hh)];
            float sA, cA;
            __sincosf(-cpi * (float)jj / (float)h, &sA, &cA);
            const float2 twA1 = make_float2(cA, sA);
            const float2 twA2 = make_float2(sA, -cA);
            const float2 twB  = make_float2(2.0f * cA * cA - 1.0f, 2.0f * sA * cA);
            float2 a0 = make_float2(c0.x + c2.x, c0.y + c2.y);
            float2 a1 = make_float2(c1.x + c3.x, c1.y + c3.y);
            float2 b0 = cmul(make_float2(c0.x - c2.x, c0.y - c2.y), twA1);
            float2 b1 = cmul(make_float2(c1.x - c3.x, c1.y - c3.y), twA2);
            cbuf[PAD(i0)]          = make_float2(a0.x + a1.x, a0.y + a1.y);
            cbuf[PAD(i0 + hh)]     = cmul(make_float2(a0.x - a1.x, a0.y - a1.y), twB);
            cbuf[PAD(i0 + h)]      = make_float2(b0.x + b1.x, b0.y + b1.y);
            cbuf[PAD(i0 + h + hh)] = cmul(make_float2(b0.x - b1.x, b0.y - b1.y), twB);
        }
        __syncthreads();
    }

    {
        #pragma unroll
        for (int v = 0; v < 4; ++v) {
            const int u = t + v * 512;
            if (u == 0) {
                {
                    float2 g0 = cbuf[0], g1 = cbuf[1];
                    float2 Pa = make_float2(g0.x + g1.x, g0.y + g1.y);
                    float2 Pb = make_float2(g0.x - g1.x, g0.y - g1.y);
                    float2 Ra = Pa;
                    float Sb = 0.5f * (Eh1 + Eh2), Db = 0.5f * (Eh1 - Eh2);
                    float2 Rb = sdmix(Sb, Db, Pb, Pb);
                    cbuf[0] = make_float2(Ra.x + Rb.x, Ra.y + Rb.y);
                    cbuf[1] = make_float2(Ra.x - Rb.x, Ra.y - Rb.y);
                }
                {
                    float wu = c2pi * 2048.0f / 8191.0f;
                    float h1 = __expf(-wu * d1), h2 = __expf(-wu * d2);
                    float h1b = h1 * Eh1, h2b = h2 * Eh2;
                    float Hs1a = 0.5f * (h1 + E1 / h1);
                    float Hs2a = 0.5f * (h2 + E2 / h2);
                    float Hs1b = 0.5f * (h1b + E1 / h1b);
                    float Hs2b = 0.5f * (h2b + E2 / h2b);
                    float Sa = 0.5f * (Hs1a + Hs2a), Da = 0.5f * (Hs1a - Hs2a);
                    float Sb = 0.5f * (Hs1b + Hs2b), Db = 0.5f * (Hs1b - Hs2b);
                    float2 g0 = cbuf[2], g1 = cbuf[3];
                    float2 Pa = make_float2(g0.x + g1.x, g0.y + g1.y);
                    float2 Pb = make_float2(g0.x - g1.x, g0.y - g1.y);
                    float2 Ra = sdmix(Sa, Da, Pa, Pb);
                    float2 Rb = sdmix(Sb, Db, Pb, Pa);
                    cbuf[2] = make_float2(Ra.x + Rb.x, Ra.y + Rb.y);
                    cbuf[3] = make_float2(Ra.x - Rb.x, Ra.y - Rb.y);
                }
            } else {
                const int u2 = 4096 - u;
                const int c  = (int)(__brev((unsigned)u)  >> 20);
                const int c2 = (int)(__brev((unsigned)u2) >> 20);
                const int s0 = PAD(2 * c),  s1 = PAD(2 * c + 1);
                const int s2 = PAD(2 * c2), s3 = PAD(2 * c2 + 1);
                float2 g0 = cbuf[s0], g1 = cbuf[s1];
                float2 q0 = cbuf[s2], q1 = cbuf[s3];
                float2 Pa  = make_float2(g0.x + g1.x, g0.y + g1.y);
                float2 Pb  = make_float2(g0.x - g1.x, g0.y - g1.y);
                float2 Pa2 = make_float2(q0.x + q1.x, q0.y + q1.y);
                float2 Pb2 = make_float2(q0.x - q1.x, q0.y - q1.y);
                float wu = c2pi * (float)u / 8191.0f;
                float h1 = __expf(-wu * d1), h2 = __expf(-wu * d2);
                float h1b = h1 * Eh1, h2b = h2 * Eh2;
                float Hs1a = 0.5f * (h1 + E1 / h1);
                float Hs2a = 0.5f * (h2 + E2 / h2);
                float Hs1b = 0.5f * (h1b + E1 / h1b);
                float Hs2b = 0.5f * (h2b + E2 / h2b);
                float Sa = 0.5f * (Hs1a + Hs2a), Da = 0.5f * (Hs1a - Hs2a);
                float Sb = 0.5f * (Hs1b + Hs2b), Db = 0.5f * (Hs1b - Hs2b);
                float2 Ra  = sdmix(Sa, Da, Pa,  Pb2);
                float2 Rb2 = sdmix(Sa, Da, Pb2, Pa);
                float2 Rb  = sdmix(Sb, Db, Pb,  Pa2);
                float2 Ra2 = sdmix(Sb, Db, Pa2, Pb);
                cbuf[s0] = make_float2(Ra.x + Rb.x,   Ra.y + Rb.y);
                cbuf[s1] = make_float2(Ra.x - Rb.x,   Ra.y - Rb.y);
                cbuf[s2] = make_float2(Ra2.x + Rb2.x, Ra2.y + Rb2.y);
                cbuf[s3] = make_float2(Ra2.x - Rb2.x, Ra2.y - Rb2.y);
            }
        }
        __syncthreads();
    }

    #pragma unroll
    for (int h = 2; h <= 512; h <<= 2) {
        #pragma unroll
        for (int u = 0; u < 4; ++u) {
            const int q  = t + u * 512;
            const int jj = q & (h - 1);
            const int i0 = ((q - jj) << 2) + jj;
            float2 c0 = cbuf[PAD(i0)];
            float2 c1 = cbuf[PAD(i0 + h)];
            float2 c2 = cbuf[PAD(i0 + 2 * h)];
            float2 c3 = cbuf[PAD(i0 + 3 * h)];
            float sa, ca;
            __sincosf(cpi * (float)jj / (float)(2 * h), &sa, &ca);
            const float2 tw1  = make_float2(2.0f * ca * ca - 1.0f, 2.0f * sa * ca);
            const float2 tw2a = make_float2(ca, sa);
            const float2 tw2b = make_float2(-sa, ca);
            float2 t0 = cmul(c1, tw1);
            float2 a0 = make_float2(c0.x + t0.x, c0.y + t0.y);
            float2 a1 = make_float2(c0.x - t0.x, c0.y - t0.y);
            float2 t1 = cmul(c3, tw1);
            float2 b0 = make_float2(c2.x + t1.x, c2.y + t1.y);
            float2 b1 = make_float2(c2.x - t1.x, c2.y - t1.y);
            float2 t2 = cmul(b0, tw2a);
            cbuf[PAD(i0)]         = make_float2(a0.x + t2.x, a0.y + t2.y);
            cbuf[PAD(i0 + 2 * h)] = make_float2(a0.x - t2.x, a0.y - t2.y);
            float2 t3 = cmul(b1, tw2b);
            cbuf[PAD(i0 + h)]     = make_float2(a1.x + t3.x, a1.y + t3.y);
            cbuf[PAD(i0 + 3 * h)] = make_float2(a1.x - t3.x, a1.y - t3.y);
        }
        __syncthreads();
    }

    {
        const int h = 2048;
        const float inv = 1.0f / (float)N_;
        #pragma unroll
        for (int u = 0; u < 4; ++u) {
            const int jj = t + u * 512;
            const int i0 = jj;
            float2 c0 = cbuf[PAD(i0)];
            float2 c1 = cbuf[PAD(i0 + h)];
            float2 c2 = cbuf[PAD(i0 + 2 * h)];
            float2 c3 = cbuf[PAD(i0 + 3 * h)];
            float sa, ca;
            __sincosf(cpi * (float)jj / (float)(2 * h), &sa, &ca);
            const float2 tw1  = make_float2(2.0f * ca * ca - 1.0f, 2.0f * sa * ca);
            const float2 tw2a = make_float2(ca, sa);
            const float2 tw2b = make_float2(-sa, ca);
            float2 t0 = cmul(c1, tw1);
            float2 a0 = make_float2(c0.x + t0.x, c0.y + t0.y);
            float2 a1 = make_float2(c0.x - t0.x, c0.y - t0.y);
            float2 t1 = cmul(c3, tw1);
            float2 b0 = make_float2(c2.x + t1.x, c2.y + t1.y);
            float2 b1 = make_float2(c2.x - t1.x, c2.y - t1.y);
            float2 t2 = cmul(b0, tw2a);
            float2 o0 = make_float2(a0.x + t2.x, a0.y + t2.y);
            float2 o2 = make_float2(a0.x - t2.x, a0.y - t2.y);
            float2 t3 = cmul(b1, tw2b);
            float2 o1 = make_float2(a1.x + t3.x, a1.y + t3.y);
            float2 o3 = make_float2(a1.x - t3.x, a1.y - t3.y);
            row1[i0]         = o0.x * inv;  row2[i0]         = o0.y * inv;
            row1[i0 + h]     = o1.x * inv;  row2[i0 + h]     = o1.y * inv;
            row1[i0 + 2*h]   = o2.x * inv;  row2[i0 + 2*h]   = o2.y * inv;
            row1[i0 + 3*h]   = o3.x * inv;  row2[i0 + 3*h]   = o3.y * inv;
        }
    }
}

// ---------------------------------------------------------------------------
// K5: t[b,n,r] = sum_k y[b,k,n]·U[k,r];  out = x + t @ G^T + bu (r15 ver).
// ---------------------------------------------------------------------------
__global__ __launch_bounds__(256)
void out_kernel(const float* __restrict__ x,
                const float* __restrict__ y_t,
                const float* __restrict__ U,
                const float* __restrict__ G,
                const float* __restrict__ bu,
                float*       __restrict__ out) {
    __shared__ float ttile[64][R_ + 1];
    const int blk = blockIdx.x;          // 2048
    const int b   = blk >> 7;
    const int n0  = (blk & 127) << 6;
    const int t   = threadIdx.x;

    {
        const int r = t >> 6, nl = t & 63;
        const float* yb = y_t + (size_t)b * BN_ * N_ + n0 + nl;
        float s = 0.0f;
        #pragma unroll
        for (int kk = 0; kk < BN_; ++kk) s += yb[(size_t)kk * N_] * U[kk * R_ + r];
        ttile[nl][r] = s;
    }
    __syncthreads();

    const int d4 = t & 63, rg = t >> 6;
    const float4 g0 = *(const float4*)(G + (d4 * 4 + 0) * 4);
    const float4 g1 = *(const float4*)(G + (d4 * 4 + 1) * 4);
    const float4 g2 = *(const float4*)(G + (d4 * 4 + 2) * 4);
    const float4 g3 = *(const float4*)(G + (d4 * 4 + 3) * 4);
    const float4 bv = *(const float4*)(bu + d4 * 4);
    const float4* xb = (const float4*)(x   + ((size_t)(b * N_ + n0)) * D_);
    float4*       ob = (float4*)      (out + ((size_t)(b * N_ + n0)) * D_);
    #pragma unroll 4
    for (int nl = rg; nl < 64; nl += 4) {
        const float t0 = ttile[nl][0], t1 = ttile[nl][1];
        const float t2 = ttile[nl][2], t3 = ttile[nl][3];
        const float4 xv = xb[nl * 64 + d4];
        float4 o;
        o.x = xv.x + t0 * g0.x + t1 * g0.y + t2 * g0.z + t3 * g0.w + bv.x;
        o.y = xv.y + t0 * g1.x + t1 * g1.y + t2 * g1.z + t3 * g1.w + bv.y;
        o.z = xv.z + t0 * g2.x + t1 * g2.y + t2 * g2.z + t3 * g2.w + bv.z;
        o.w = xv.w + t0 * g3.x + t1 * g3.y + t2 * g3.z + t3 * g3.w + bv.w;
        ob[nl * 64 + d4] = o;
    }
}

// ---------------------------------------------------------------------------
extern "C" void kernel_launch(void* const* d_in, const int* in_sizes, int n_in,
                              void* d_out, int out_size, void* d_ws, size_t ws_size,
                              hipStream_t stream) {
    const float* x       = (const float*)d_in[0];
    const float* coords  = (const float*)d_in[1];
    const float* Wd      = (const float*)d_in[2];
    const float* bd      = (const float*)d_in[3];
    const float* U       = (const float*)d_in[4];
    const float* V       = (const float*)d_in[5];
    const float* logit_d = (const float*)d_in[6];
    const float* Wu      = (const float*)d_in[7];
    const float* bu      = (const float*)d_in[8];
    float* out = (float*)d_out;

    char* ws = (char*)d_ws;
    int*   order = (int*)ws;                             // 512 KB
    ull*   keys  = (ull*)(ws + 512 * 1024);              // 1 MB
    float* G     = (float*)(ws + 1536 * 1024);           // 4 KB
    float* zpk   = (float*)(ws + 2048 * 1024);           // 16 MB
    float* zkp   = (float*)(ws + (2048 + 16384) * 1024); // 16 MB

    fat_kernel   <<<dim3(2 * B_ + 1024), dim3(512), 32 * 1024, stream>>>(x, coords, Wd, keys, zpk);
    sort2_kernel <<<dim3(2 * B_),        dim3(512), 0, stream>>>(keys, order);
    zgather_kernel<<<dim3(B_ * 128),     dim3(512), 0, stream>>>(zpk, coords, Wd, bd, order, Wu, V, G, zkp);
    fft_filter_kernel<<<dim3(B_ * 16),   dim3(512), 8704 * 8, stream>>>(zkp, logit_d);
    out_kernel   <<<dim3(B_ * 128),      dim3(256), 0, stream>>>(x, zkp, U, G, bu, out);
}